// Round 7
// baseline (678.968 us; speedup 1.0000x reference)
//
#include <hip/hip_runtime.h>

typedef __bf16 bf16f __attribute__((ext_vector_type(8)));
typedef float  f32x4 __attribute__((ext_vector_type(4)));

__device__ __forceinline__ float bf2f(unsigned short u) {
  union { unsigned int u; float f; } v;
  v.u = ((unsigned int)u) << 16;
  return v.f;
}
__device__ __forceinline__ unsigned short f2bf(float f) {
  union { float f; unsigned int u; } v; v.f = f;
  unsigned int r = v.u + 0x7FFFu + ((v.u >> 16) & 1u);
  return (unsigned short)(r >> 16);
}
// exact unpack of packed bf16 pair (no rounding involved)
__device__ __forceinline__ float bflo(unsigned int w) {
  union { unsigned int u; float f; } v; v.u = w << 16; return v.f;
}
__device__ __forceinline__ float bfhi(unsigned int w) {
  union { unsigned int u; float f; } v; v.u = w & 0xFFFF0000u; return v.f;
}

// zero the degree counters (canonical kernel symbol kept here)
__global__ void GNNModel_general_12077448036407_kernel(int* cnt, int ncnt) {
  int i = blockIdx.x * blockDim.x + threadIdx.x;
  if (i < ncnt) cnt[i] = 0;
}

// ---- weight prepack + scan flag zero: lw1/lw2 -> bf16 [Nt][K]; W2 hi/lo ----
__global__ void wpack3_kernel(const float* __restrict__ lw1, unsigned short* __restrict__ Wb1,
                              const float* __restrict__ lw2, unsigned short* __restrict__ Wb2,
                              const float* __restrict__ W2, unsigned short* __restrict__ W2h,
                              unsigned short* __restrict__ W2l,
                              int* __restrict__ scanws) {
  int i = blockIdx.x * blockDim.x + threadIdx.x;
  if (i < 512) scanws[i] = 0;      // [0,256)=psum, [256,512)=flag for scanc
  if (i < 512 * 128) {             // Wb1[n][k], n<512, k<128; lw1 is [128][512]
    int n = i >> 7, k = i & 127;
    Wb1[i] = f2bf(lw1[(size_t)k * 512 + n]);
  }
  if (i < 256 * 512) {             // Wb2[n][k], n<256, k<512; lw2 is [512][256]
    int n = i >> 9, k = i & 511;
    Wb2[i] = f2bf(lw2[(size_t)k * 256 + n]);
  }
  if (i < 128 * 128) {             // W2h/W2l[n][k]; W2 is [128][128]
    int n = i >> 7, k = i & 127;
    float w = W2[(size_t)k * 128 + n];
    unsigned short h = f2bf(w);
    W2h[i] = h;
    W2l[i] = f2bf(w - bf2f(h));
  }
}

// ---------------- F1: layer-1 GEMM (blocks [0,gblocks)) || rank (rest) ------
// tgemm1: hb[M,128] = bf16(x[M,64] @ W1[64,128]); rank: degree count + rank.
// The rank blocks are atomic-latency-bound (VALU ~0%); co-residency with the
// compute-bound GEMM blocks hides the GEMM entirely under the atomic pass.
// NOTE: keep this epilogue minimal — fusing alphas here (round 4) pushed the
// critical dispatch 80->93 us; alphas1 rides the place launch instead.
__launch_bounds__(256)
__global__ void gr_fused_kernel(const float* __restrict__ x, const float* __restrict__ W1,
                                unsigned short* __restrict__ hb, int M, int gblocks,
                                const int* __restrict__ dst, int* __restrict__ cnt,
                                unsigned short* __restrict__ rank, int E) {
  __shared__ float As[16][132];
  __shared__ float Bs[16][136];
  int bid = blockIdx.x;
  int t = threadIdx.x;

  if (bid >= gblocks) {
    int e = (bid - gblocks) * 256 + t;
    if (e < E) {
      int r = atomicAdd(&cnt[dst[e]], 1);
      rank[e] = (unsigned short)r;
    }
    return;
  }

  // ---- tgemm specialized: K=64, Nt=128, A f32, C bf16, no bias, no relu ----
  int tx = t & 15, ty = t >> 4;
  int m0 = bid * 128;

  float acc[8][8];
#pragma unroll
  for (int i = 0; i < 8; i++)
#pragma unroll
    for (int j = 0; j < 8; j++) acc[i][j] = 0.0f;

  int arow = t >> 1;
  int akc  = (t & 1) * 8;
  int bkk  = t >> 4;
  int bnn  = (t & 15) * 8;
  int gm = m0 + arow;

  for (int k0 = 0; k0 < 64; k0 += 16) {
    float av[8];
    if (gm < M) {
      const float* Af = x + (size_t)gm * 64 + k0 + akc;
      float4 r0 = *(const float4*)Af;
      float4 r1 = *(const float4*)(Af + 4);
      av[0] = r0.x; av[1] = r0.y; av[2] = r0.z; av[3] = r0.w;
      av[4] = r1.x; av[5] = r1.y; av[6] = r1.z; av[7] = r1.w;
    } else {
#pragma unroll
      for (int j = 0; j < 8; j++) av[j] = 0.0f;
    }
#pragma unroll
    for (int j = 0; j < 8; j++) As[akc + j][arow] = av[j];

    const float* bp = W1 + (size_t)(k0 + bkk) * 128 + bnn;
    float4 b0 = *(const float4*)bp;
    float4 b1 = *(const float4*)(bp + 4);
    *(float4*)&Bs[bkk][bnn]     = b0;
    *(float4*)&Bs[bkk][bnn + 4] = b1;

    __syncthreads();

#pragma unroll 4
    for (int kk = 0; kk < 16; kk++) {
      float a[8], b[8];
      *(float4*)&a[0] = *(const float4*)&As[kk][ty * 8];
      *(float4*)&a[4] = *(const float4*)&As[kk][ty * 8 + 4];
      *(float4*)&b[0] = *(const float4*)&Bs[kk][tx * 8];
      *(float4*)&b[4] = *(const float4*)&Bs[kk][tx * 8 + 4];
#pragma unroll
      for (int i = 0; i < 8; i++)
#pragma unroll
        for (int j = 0; j < 8; j++)
          acc[i][j] = fmaf(a[i], b[j], acc[i][j]);
    }
    __syncthreads();
  }

#pragma unroll
  for (int i = 0; i < 8; i++) {
    int m = m0 + ty * 8 + i;
    if (m >= M) continue;
    unsigned short* Cp = hb + (size_t)m * 128 + tx * 8;
    uint4 pk;
    pk.x = (unsigned int)f2bf(acc[i][0]) | ((unsigned int)f2bf(acc[i][1]) << 16);
    pk.y = (unsigned int)f2bf(acc[i][2]) | ((unsigned int)f2bf(acc[i][3]) << 16);
    pk.z = (unsigned int)f2bf(acc[i][4]) | ((unsigned int)f2bf(acc[i][5]) << 16);
    pk.w = (unsigned int)f2bf(acc[i][6]) | ((unsigned int)f2bf(acc[i][7]) << 16);
    *(uint4*)Cp = pk;
  }
}

// ---------------- single-launch chained exclusive scan ----------------------
// 196 blocks (<= CU count -> all co-resident, spin-wait safe). Device-scope
// atomics for cross-XCD visibility of psum/flag.
__global__ void scanc_kernel(const int* __restrict__ cnt, int* __restrict__ offs,
                             int* __restrict__ scanws, int M) {
  __shared__ int sh[256];
  __shared__ int prev;
  int* psum = scanws;
  int* flag = scanws + 256;
  int b = blockIdx.x, t = threadIdx.x;
  int i = b * 256 + t;
  int v = (i < M) ? cnt[i] : 0;
  sh[t] = v;
  __syncthreads();
  for (int off = 1; off < 256; off <<= 1) {
    int u = (t >= off) ? sh[t - off] : 0;
    __syncthreads();
    sh[t] += u;
    __syncthreads();
  }
  if (t == 0) {
    int p = 0;
    if (b > 0) {
      while (atomicAdd(&flag[b - 1], 0) == 0) { }
      p = atomicAdd(&psum[b - 1], 0);
    }
    prev = p;
    atomicExch(&psum[b], p + sh[255]);
    __threadfence();
    atomicExch(&flag[b], 1);
  }
  __syncthreads();
  if (i <= M) offs[i] = prev + sh[t] - v;
}

// ---------------- F2: alphas layer1 (blocks [0,ablocks)) || place (rest) ----
__global__ void pa_fused_kernel(const unsigned short* __restrict__ hb,
                                const float* __restrict__ a_src,
                                const float* __restrict__ a_dst,
                                float2* __restrict__ aSp, float2* __restrict__ aDp,
                                int M, int ablocks,
                                const int* __restrict__ src, const int* __restrict__ dstp,
                                const unsigned short* __restrict__ rank,
                                const int* __restrict__ offs, int* __restrict__ csr, int E) {
  int bid = blockIdx.x;
  int t = threadIdx.x;

  if (bid >= ablocks) {
    int e = (bid - ablocks) * 256 + t;
    if (e < E) {
      int p = offs[dstp[e]] + (int)rank[e];
      __builtin_nontemporal_store(src[e], &csr[p]);
    }
    return;
  }

  int gw = (bid * 256 + t) >> 6;
  int lane = t & 63;
  if (gw >= M) return;
  float h0 = bf2f(hb[(size_t)gw * 128 + lane]);
  float h1 = bf2f(hb[(size_t)gw * 128 + 64 + lane]);
  float as0 = h0 * a_src[lane];
  float as1 = h1 * a_src[64 + lane];
  float ad0 = h0 * a_dst[lane];
  float ad1 = h1 * a_dst[64 + lane];
  for (int o = 32; o; o >>= 1) {
    as0 += __shfl_xor(as0, o);
    as1 += __shfl_xor(as1, o);
    ad0 += __shfl_xor(ad0, o);
    ad1 += __shfl_xor(ad1, o);
  }
  if (lane == 0) {
    aSp[gw] = make_float2(as0, as1);
    aDp[gw] = make_float2(ad0, ad1);
  }
}

// ---------------- MFMA bf16 GEMM, m97 structure (MLP path) -------------------
// 128x128 tile, BK=32, 4 waves (2x2), 4x4 fragments of 16x16x32 per wave.
// B prepacked bf16 [Nt][K] staged via global_load_lds width=16; A direct-to-LDS
// when bf16, reg-staged f32->bf16 when f32. XCD-chunked work map (blockIdx.x =
// XCD = linear id % 8) so each A panel is fetched into exactly one XCD L2.
// Epilogue: two-pass LDS re-layout then cooperative uint4 stores (full 128B
// HBM lines; direct 2B stores caused 2.4x write amplification).
__launch_bounds__(256)
__global__ void m128_kernel(const void* __restrict__ A,
                            const unsigned short* __restrict__ Bw,
                            const float* __restrict__ bias, void* __restrict__ C,
                            int M, int K, int Nt, int aBF, int cBF, int relu,
                            int mtiles, int lgNB) {
  __shared__ unsigned short sh[8704];            // staging 16 KB / epilogue 128x68
  unsigned short* As = sh;                       // 128*32
  unsigned short* Bs = sh + 4096;                // 128*32
  int tid = threadIdx.x;
  int wid = tid >> 6, lane = tid & 63;
  int lm = lane & 15, quad = lane >> 4;
  int wr = wid >> 1, wc = wid & 1;

  // ---- XCD-chunked (m,n) tile assignment ----
  int xcd = blockIdx.x;                          // == linear dispatch id % 8
  int slot = blockIdx.y;
  int qm = mtiles >> 3, rm = mtiles & 7;
  int cntm = qm + (xcd < rm);
  int mstart = xcd * qm + (xcd < rm ? xcd : rm);
  if (slot >= (cntm << lgNB)) return;
  int NBm1 = (1 << lgNB) - 1;
  int m0 = (mstart + (slot >> lgNB)) * 128;
  int n0 = (slot & NBm1) * 128;

  f32x4 acc[4][4];
#pragma unroll
  for (int mi = 0; mi < 4; mi++)
#pragma unroll
    for (int ni = 0; ni < 4; ni++)
#pragma unroll
      for (int i = 0; i < 4; i++) acc[mi][ni][i] = 0.0f;

  // staging ids
  int c0 = (wid << 6) + lane;       // chunk ids for direct-to-LDS 16B loads
  int c1 = c0 + 256;
  int srow = tid >> 1;              // reg-stage (aBF=0): row 0..127
  int skc  = (tid & 1) << 4;        // k sub-offset 0/16 (16 floats each)

  for (int k0 = 0; k0 < K; k0 += 32) {
    // ---- B tile: 128 n-rows x 32 k, linear LDS, 2x global_load_lds / thread
    {
      const unsigned short* g0 = Bw + (size_t)(n0 + (c0 >> 2)) * K + k0 + ((c0 & 3) << 3);
      __builtin_amdgcn_global_load_lds((const __attribute__((address_space(1))) void*)g0,
                                       (__attribute__((address_space(3))) void*)(Bs + (wid << 9)),
                                       16, 0, 0);
      const unsigned short* g1 = Bw + (size_t)(n0 + (c1 >> 2)) * K + k0 + ((c1 & 3) << 3);
      __builtin_amdgcn_global_load_lds((const __attribute__((address_space(1))) void*)g1,
                                       (__attribute__((address_space(3))) void*)(Bs + 2048 + (wid << 9)),
                                       16, 0, 0);
    }
    // ---- A tile
    if (aBF) {
      int r0 = m0 + (c0 >> 2); if (r0 > M - 1) r0 = M - 1;   // clamp tail (rows >= M never written)
      const unsigned short* g0 = (const unsigned short*)A + (size_t)r0 * K + k0 + ((c0 & 3) << 3);
      __builtin_amdgcn_global_load_lds((const __attribute__((address_space(1))) void*)g0,
                                       (__attribute__((address_space(3))) void*)(As + (wid << 9)),
                                       16, 0, 0);
      int r1 = m0 + (c1 >> 2); if (r1 > M - 1) r1 = M - 1;
      const unsigned short* g1 = (const unsigned short*)A + (size_t)r1 * K + k0 + ((c1 & 3) << 3);
      __builtin_amdgcn_global_load_lds((const __attribute__((address_space(1))) void*)g1,
                                       (__attribute__((address_space(3))) void*)(As + 2048 + (wid << 9)),
                                       16, 0, 0);
    } else {
      int gm = m0 + srow;
      uint4 p0, p1;
      if (gm < M) {
        const float* Af = (const float*)A + (size_t)gm * K + k0 + skc;
        float4 r0 = *(const float4*)Af;
        float4 r1 = *(const float4*)(Af + 4);
        float4 r2 = *(const float4*)(Af + 8);
        float4 r3 = *(const float4*)(Af + 12);
        p0.x = (unsigned int)f2bf(r0.x) | ((unsigned int)f2bf(r0.y) << 16);
        p0.y = (unsigned int)f2bf(r0.z) | ((unsigned int)f2bf(r0.w) << 16);
        p0.z = (unsigned int)f2bf(r1.x) | ((unsigned int)f2bf(r1.y) << 16);
        p0.w = (unsigned int)f2bf(r1.z) | ((unsigned int)f2bf(r1.w) << 16);
        p1.x = (unsigned int)f2bf(r2.x) | ((unsigned int)f2bf(r2.y) << 16);
        p1.y = (unsigned int)f2bf(r2.z) | ((unsigned int)f2bf(r2.w) << 16);
        p1.z = (unsigned int)f2bf(r3.x) | ((unsigned int)f2bf(r3.y) << 16);
        p1.w = (unsigned int)f2bf(r3.z) | ((unsigned int)f2bf(r3.w) << 16);
      } else {
        p0.x = p0.y = p0.z = p0.w = 0u;
        p1.x = p1.y = p1.z = p1.w = 0u;
      }
      *(uint4*)&As[srow * 32 + skc] = p0;
      *(uint4*)&As[srow * 32 + skc + 8] = p1;
    }
    __syncthreads();

    bf16f afr[4], bfr[4];
#pragma unroll
    for (int mi = 0; mi < 4; mi++)
      afr[mi] = *(const bf16f*)&As[(wr * 64 + mi * 16 + lm) * 32 + quad * 8];
#pragma unroll
    for (int ni = 0; ni < 4; ni++)
      bfr[ni] = *(const bf16f*)&Bs[(wc * 64 + ni * 16 + lm) * 32 + quad * 8];
#pragma unroll
    for (int mi = 0; mi < 4; mi++)
#pragma unroll
      for (int ni = 0; ni < 4; ni++)
        acc[mi][ni] = __builtin_amdgcn_mfma_f32_16x16x32_bf16(afr[mi], bfr[ni], acc[mi][ni], 0, 0, 0);
    __syncthreads();
  }

  if (cBF) {
    // ---- two-pass LDS-staged coalesced bf16 epilogue ----
#pragma unroll
    for (int p = 0; p < 2; p++) {
      __syncthreads();
      if (wc == p) {
#pragma unroll
        for (int ni = 0; ni < 4; ni++) {
          int colb = ni * 16 + lm;                      // 0..63 within pass
          float bv = (bias != 0) ? bias[n0 + p * 64 + colb] : 0.0f;
#pragma unroll
          for (int mi = 0; mi < 4; mi++) {
#pragma unroll
            for (int i = 0; i < 4; i++) {
              int rowb = wr * 64 + mi * 16 + quad * 4 + i;
              float v = acc[mi][ni][i] + bv;
              if (relu) v = fmaxf(v, 0.0f);
              sh[rowb * 68 + colb] = f2bf(v);
            }
          }
        }
      }
      __syncthreads();
#pragma unroll
      for (int sweep = 0; sweep < 4; sweep++) {
        int rowb = (tid >> 3) + 32 * sweep;
        int seg = tid & 7;
        int grow = m0 + rowb;
        if (grow < M) {
          uint4 val = *(const uint4*)&sh[rowb * 68 + seg * 8];
          *(uint4*)((unsigned short*)C + (size_t)grow * Nt + n0 + p * 64 + seg * 8) = val;
        }
      }
    }
  } else {
    // f32 fallback (unused in current launches)
#pragma unroll
    for (int ni = 0; ni < 4; ni++) {
      int col = n0 + wc * 64 + ni * 16 + lm;
      float bv = (bias != 0) ? bias[col] : 0.0f;
#pragma unroll
      for (int mi = 0; mi < 4; mi++) {
#pragma unroll
        for (int i = 0; i < 4; i++) {
          int row = m0 + wr * 64 + mi * 16 + quad * 4 + i;
          if (row < M) {
            float v = acc[mi][ni][i] + bv;
            if (relu) v = fmaxf(v, 0.0f);
            ((float*)C)[(size_t)row * Nt + col] = v;
          }
        }
      }
    }
  }
}

// ---------------- layer-2 GEMM: 3-term split-precision bf16 MFMA ------------
// hb[M,128] = bf16(x2[M,128] @ W2[128,128]), f32-class accuracy.
// A comes prepacked hi/lo bf16 from aggregate1 (x2h/x2l); all tiles stage via
// global_load_lds. BM=64, 4 waves 2x2, fused alphas2.
__launch_bounds__(256)
__global__ void tg2m_kernel(const unsigned short* __restrict__ Ahp,
                            const unsigned short* __restrict__ Alp,
                            const unsigned short* __restrict__ Bh,
                            const unsigned short* __restrict__ Bl,
                            const float* __restrict__ a_src, const float* __restrict__ a_dst,
                            unsigned short* __restrict__ hb,
                            float2* __restrict__ aSp, float2* __restrict__ aDp,
                            int M) {
  __shared__ unsigned short sh[12288];          // 24 KB
  unsigned short* Ah = sh;                      // 64*32
  unsigned short* Al = sh + 2048;
  unsigned short* BH = sh + 4096;               // 128*32
  unsigned short* BL = sh + 8192;
  const int K = 128;
  int tid = threadIdx.x;
  int wid = tid >> 6, lane = tid & 63;
  int lm = lane & 15, quad = lane >> 4;
  int wr = wid >> 1, wc = wid & 1;
  int m0 = blockIdx.x * 64;

  f32x4 acc[2][4];
#pragma unroll
  for (int mi = 0; mi < 2; mi++)
#pragma unroll
    for (int ni = 0; ni < 4; ni++)
#pragma unroll
      for (int i = 0; i < 4; i++) acc[mi][ni][i] = 0.0f;

  int c0 = (wid << 6) + lane, c1 = c0 + 256;

  for (int k0 = 0; k0 < K; k0 += 32) {
    // B hi/lo tiles: 128 n-rows x 32 k each, direct-to-LDS
    {
      const unsigned short* g0 = Bh + (size_t)(c0 >> 2) * K + k0 + ((c0 & 3) << 3);
      __builtin_amdgcn_global_load_lds((const __attribute__((address_space(1))) void*)g0,
                                       (__attribute__((address_space(3))) void*)(BH + (wid << 9)),
                                       16, 0, 0);
      const unsigned short* g1 = Bh + (size_t)(c1 >> 2) * K + k0 + ((c1 & 3) << 3);
      __builtin_amdgcn_global_load_lds((const __attribute__((address_space(1))) void*)g1,
                                       (__attribute__((address_space(3))) void*)(BH + 2048 + (wid << 9)),
                                       16, 0, 0);
      const unsigned short* g2 = Bl + (size_t)(c0 >> 2) * K + k0 + ((c0 & 3) << 3);
      __builtin_amdgcn_global_load_lds((const __attribute__((address_space(1))) void*)g2,
                                       (__attribute__((address_space(3))) void*)(BL + (wid << 9)),
                                       16, 0, 0);
      const unsigned short* g3 = Bl + (size_t)(c1 >> 2) * K + k0 + ((c1 & 3) << 3);
      __builtin_amdgcn_global_load_lds((const __attribute__((address_space(1))) void*)g3,
                                       (__attribute__((address_space(3))) void*)(BL + 2048 + (wid << 9)),
                                       16, 0, 0);
    }
    // A hi/lo tiles: 64 rows x 32 k, direct-to-LDS (256 chunks = whole tile)
    {
      int r0 = m0 + (c0 >> 2); if (r0 > M - 1) r0 = M - 1;   // tail clamp
      const unsigned short* g0 = Ahp + (size_t)r0 * K + k0 + ((c0 & 3) << 3);
      __builtin_amdgcn_global_load_lds((const __attribute__((address_space(1))) void*)g0,
                                       (__attribute__((address_space(3))) void*)(Ah + (wid << 9)),
                                       16, 0, 0);
      const unsigned short* g1 = Alp + (size_t)r0 * K + k0 + ((c0 & 3) << 3);
      __builtin_amdgcn_global_load_lds((const __attribute__((address_space(1))) void*)g1,
                                       (__attribute__((address_space(3))) void*)(Al + (wid << 9)),
                                       16, 0, 0);
    }
    __syncthreads();

    bf16f ahf[2], alf[2];
#pragma unroll
    for (int mi = 0; mi < 2; mi++) {
      ahf[mi] = *(const bf16f*)&Ah[(wr * 32 + mi * 16 + lm) * 32 + quad * 8];
      alf[mi] = *(const bf16f*)&Al[(wr * 32 + mi * 16 + lm) * 32 + quad * 8];
    }
#pragma unroll
    for (int ni = 0; ni < 4; ni++) {
      bf16f vbh = *(const bf16f*)&BH[(wc * 64 + ni * 16 + lm) * 32 + quad * 8];
      bf16f vbl = *(const bf16f*)&BL[(wc * 64 + ni * 16 + lm) * 32 + quad * 8];
#pragma unroll
      for (int mi = 0; mi < 2; mi++) {
        acc[mi][ni] = __builtin_amdgcn_mfma_f32_16x16x32_bf16(ahf[mi], vbh, acc[mi][ni], 0, 0, 0);
        acc[mi][ni] = __builtin_amdgcn_mfma_f32_16x16x32_bf16(alf[mi], vbh, acc[mi][ni], 0, 0, 0);
        acc[mi][ni] = __builtin_amdgcn_mfma_f32_16x16x32_bf16(ahf[mi], vbl, acc[mi][ni], 0, 0, 0);
      }
    }
    __syncthreads();
  }

  // ---- epilogue: two col-passes; coalesced hb stores + fused alphas --------
  float ps[2], pd[2];
#pragma unroll
  for (int p = 0; p < 2; p++) {
    __syncthreads();
    if (wc == p) {
#pragma unroll
      for (int ni = 0; ni < 4; ni++) {
        int colb = ni * 16 + lm;
#pragma unroll
        for (int mi = 0; mi < 2; mi++)
#pragma unroll
          for (int i = 0; i < 4; i++) {
            int rowb = wr * 32 + mi * 16 + quad * 4 + i;
            sh[rowb * 72 + colb] = f2bf(acc[mi][ni][i]);
          }
      }
    }
    __syncthreads();
    // coalesced store: 64 rows x 64 cols (8 x uint4 per row)
#pragma unroll
    for (int sweep = 0; sweep < 2; sweep++) {
      int rowb = (tid >> 3) + 32 * sweep;
      int seg = tid & 7;
      int grow = m0 + rowb;
      if (grow < M) {
        uint4 val = *(const uint4*)&sh[rowb * 72 + seg * 8];
        *(uint4*)(hb + (size_t)grow * 128 + p * 64 + seg * 8) = val;
      }
    }
    // alphas partials for head p: 4 threads/row x 16 cols
    {
      int row = tid >> 2, sg = tid & 3;
      const float* As_ = a_src + p * 64 + sg * 16;
      const float* Ad_ = a_dst + p * 64 + sg * 16;
      float s = 0.0f, d = 0.0f;
#pragma unroll
      for (int c8 = 0; c8 < 2; c8++) {
        uint4 rv = *(const uint4*)&sh[row * 72 + sg * 16 + c8 * 8];
        const float* Ap_ = As_ + c8 * 8;
        const float* Dp_ = Ad_ + c8 * 8;
        float hv[8];
        hv[0] = bflo(rv.x); hv[1] = bfhi(rv.x);
        hv[2] = bflo(rv.y); hv[3] = bfhi(rv.y);
        hv[4] = bflo(rv.z); hv[5] = bfhi(rv.z);
        hv[6] = bflo(rv.w); hv[7] = bfhi(rv.w);
#pragma unroll
        for (int j = 0; j < 8; j++) {
          s = fmaf(hv[j], Ap_[j], s);
          d = fmaf(hv[j], Dp_[j], d);
        }
      }
      s += __shfl_xor(s, 1); s += __shfl_xor(s, 2);
      d += __shfl_xor(d, 1); d += __shfl_xor(d, 2);
      ps[p] = s; pd[p] = d;
    }
  }
  {
    int row = tid >> 2, sg = tid & 3;
    int m = m0 + row;
    if (sg == 0 && m < M) {
      aSp[m] = make_float2(ps[0], ps[1]);
      aDp[m] = make_float2(pd[0], pd[1]);
    }
  }
}

// ---------------- MFMA logits GEMM: C[M,16] = A[M,K]@W[K,16] + bias ----------
__launch_bounds__(256)
__global__ void lgemm_kernel(const unsigned short* __restrict__ A,
                             const float* __restrict__ W,
                             const float* __restrict__ bias, float* __restrict__ C,
                             int M, int K) {
  __shared__ unsigned short Bt[16 * 264];
  int tid = threadIdx.x;
  int wave = tid >> 6, lane = tid & 63;
  int lm = lane & 15, quad = lane >> 4;
  int m0 = blockIdx.x * 64;

  // stage W (K x 16 f32) -> Bt[n][k] bf16
  for (int f0 = tid * 4; f0 < K * 16; f0 += 1024) {
    float4 w4 = *(const float4*)(W + f0);
    int k = f0 >> 4, n = f0 & 15;
    Bt[(n + 0) * 264 + k] = f2bf(w4.x);
    Bt[(n + 1) * 264 + k] = f2bf(w4.y);
    Bt[(n + 2) * 264 + k] = f2bf(w4.z);
    Bt[(n + 3) * 264 + k] = f2bf(w4.w);
  }
  __syncthreads();

  f32x4 acc;
#pragma unroll
  for (int i = 0; i < 4; i++) acc[i] = 0.0f;

  int m = m0 + wave * 16 + lm;                 // A-operand row for this lane
  const unsigned short* Ap = A + (size_t)m * K;

  for (int k0 = 0; k0 < K; k0 += 32) {
    bf16f af;
#pragma unroll
    for (int j = 0; j < 8; j++) af[j] = (__bf16)0.0f;
    if (m < M) af = *(const bf16f*)(Ap + k0 + quad * 8);
    bf16f bfv = *(const bf16f*)&Bt[lm * 264 + k0 + quad * 8];
    acc = __builtin_amdgcn_mfma_f32_16x16x32_bf16(af, bfv, acc, 0, 0, 0);
  }

  float bv = bias[lm];
#pragma unroll
  for (int i = 0; i < 4; i++) {
    int row = m0 + wave * 16 + quad * 4 + i;
    if (row < M) C[(size_t)row * 16 + lm] = acc[i] + bv;
  }
}

// ---------------- per-node softmax aggregation (bf16 gather) -----------------
// Epilogue writes any of: f32 out, bf16-hi out, bf16-lo out (nullable).
__global__ void aggregate_kernel(const unsigned short* __restrict__ hb,
                                 const float2* __restrict__ aSp,
                                 const float2* __restrict__ aDp,
                                 const int* __restrict__ csr_src, const int* __restrict__ offs,
                                 const float* __restrict__ bias,
                                 float* __restrict__ outf,
                                 unsigned short* __restrict__ outh,
                                 unsigned short* __restrict__ outl, int M) {
  int n = (blockIdx.x * blockDim.x + threadIdx.x) >> 6;
  int lane = threadIdx.x & 63;
  if (n >= M) return;
  int g = lane >> 4;
  int q = lane & 15;
  int h0sel = (q < 8);

  float2 adn = aDp[n];
  float2 asn = aSp[n];
  float e0 = asn.x + adn.x; e0 = (e0 > 0.0f) ? e0 : 0.2f * e0;   // leaky_relu 0.2
  float e1 = asn.y + adn.y; e1 = (e1 > 0.0f) ? e1 : 0.2f * e1;
  float ws0 = expf(e0), ws1 = expf(e1);
  float wself = h0sel ? ws0 : ws1;

  float acc[8];
  if (g == 0) {
    uint4 rv = *(const uint4*)(hb + (size_t)n * 128 + q * 8);
    acc[0] = wself * bflo(rv.x); acc[1] = wself * bfhi(rv.x);
    acc[2] = wself * bflo(rv.y); acc[3] = wself * bfhi(rv.y);
    acc[4] = wself * bflo(rv.z); acc[5] = wself * bfhi(rv.z);
    acc[6] = wself * bflo(rv.w); acc[7] = wself * bfhi(rv.w);
  } else {
#pragma unroll
    for (int i = 0; i < 8; i++) acc[i] = 0.0f;
  }

  float lp0 = 0.0f, lp1 = 0.0f;
  int rs = offs[n], re = offs[n + 1];
  for (int base = rs; base < re; base += 64) {
    int cnt = re - base; if (cnt > 64) cnt = 64;
    int s = 0; float w0 = 0.0f, w1 = 0.0f;
    if (lane < cnt) {
      s = csr_src[base + lane];
      float2 a = aSp[s];
      float f0 = a.x + adn.x; f0 = (f0 > 0.0f) ? f0 : 0.2f * f0;
      float f1 = a.y + adn.y; f1 = (f1 > 0.0f) ? f1 : 0.2f * f1;
      w0 = expf(f0); w1 = expf(f1);
      lp0 += w0; lp1 += w1;
    }
    int jmax = (cnt + 3) >> 2;
#pragma unroll 8
    for (int j = 0; j < jmax; j++) {
      int el = 4 * j + g;
      int sj  = __shfl(s, el);
      float w0j = __shfl(w0, el);
      float w1j = __shfl(w1, el);
      float wj = h0sel ? w0j : w1j;
      uint4 rv = *(const uint4*)(hb + (size_t)sj * 128 + q * 8);
      acc[0] = fmaf(wj, bflo(rv.x), acc[0]);
      acc[1] = fmaf(wj, bfhi(rv.x), acc[1]);
      acc[2] = fmaf(wj, bflo(rv.y), acc[2]);
      acc[3] = fmaf(wj, bfhi(rv.y), acc[3]);
      acc[4] = fmaf(wj, bflo(rv.z), acc[4]);
      acc[5] = fmaf(wj, bfhi(rv.z), acc[5]);
      acc[6] = fmaf(wj, bflo(rv.w), acc[6]);
      acc[7] = fmaf(wj, bfhi(rv.w), acc[7]);
    }
  }
#pragma unroll
  for (int i = 0; i < 8; i++) {
    acc[i] += __shfl_xor(acc[i], 16);
    acc[i] += __shfl_xor(acc[i], 32);
  }
  for (int o = 32; o; o >>= 1) {
    lp0 += __shfl_xor(lp0, o);
    lp1 += __shfl_xor(lp1, o);
  }
  if (g == 0) {
    float linv = 1.0f / ((h0sel ? lp0 + ws0 : lp1 + ws1) + 1e-16f);
    const float* bp = bias + q * 8;
    float v[8];
#pragma unroll
    for (int i = 0; i < 8; i++) v[i] = fmaxf(acc[i] * linv + bp[i], 0.0f);
    if (outf) {
      float4 o0, o1;
      o0.x = v[0]; o0.y = v[1]; o0.z = v[2]; o0.w = v[3];
      o1.x = v[4]; o1.y = v[5]; o1.z = v[6]; o1.w = v[7];
      float* op = outf + (size_t)n * 128 + q * 8;
      *(float4*)op = o0;
      *(float4*)(op + 4) = o1;
    }
    if (outh) {
      unsigned short hh[8];
#pragma unroll
      for (int i = 0; i < 8; i++) hh[i] = f2bf(v[i]);
      uint4 ph;
      ph.x = (unsigned int)hh[0] | ((unsigned int)hh[1] << 16);
      ph.y = (unsigned int)hh[2] | ((unsigned int)hh[3] << 16);
      ph.z = (unsigned int)hh[4] | ((unsigned int)hh[5] << 16);
      ph.w = (unsigned int)hh[6] | ((unsigned int)hh[7] << 16);
      *(uint4*)(outh + (size_t)n * 128 + q * 8) = ph;
      if (outl) {
        unsigned short ll[8];
#pragma unroll
        for (int i = 0; i < 8; i++) ll[i] = f2bf(v[i] - bf2f(hh[i]));
        uint4 pl;
        pl.x = (unsigned int)ll[0] | ((unsigned int)ll[1] << 16);
        pl.y = (unsigned int)ll[2] | ((unsigned int)ll[3] << 16);
        pl.z = (unsigned int)ll[4] | ((unsigned int)ll[5] << 16);
        pl.w = (unsigned int)ll[6] | ((unsigned int)ll[7] << 16);
        *(uint4*)(outl + (size_t)n * 128 + q * 8) = pl;
      }
    }
  }
}

extern "C" void kernel_launch(void* const* d_in, const int* in_sizes, int n_in,
                              void* d_out, int out_size, void* d_ws, size_t ws_size,
                              hipStream_t stream) {
  const int N = in_sizes[0] / 64;   // 50000
  const int E = in_sizes[1] / 2;    // 1,600,000
  const float* x   = (const float*)d_in[0];
  const int*   ei  = (const int*)d_in[1];
  const float* W1  = (const float*)d_in[2];
  const float* as1 = (const float*)d_in[3];
  const float* ad1 = (const float*)d_in[4];
  const float* b1  = (const float*)d_in[5];
  const float* W2  = (const float*)d_in[6];
  const float* as2 = (const float*)d_in[7];
  const float* ad2 = (const float*)d_in[8];
  const float* b2  = (const float*)d_in[9];
  const float* lw1 = (const float*)d_in[10];
  const float* lb1 = (const float*)d_in[11];
  const float* lw2 = (const float*)d_in[12];
  const float* lb2 = (const float*)d_in[13];
  const float* lw3 = (const float*)d_in[14];
  const float* lb3 = (const float*)d_in[15];

  float* emb    = (float*)d_out;                    // N*128 f32
  float* logits = (float*)d_out + (size_t)N * 128;  // N*16 f32

  // ---- workspace layout ----
  // persistent (live across phases): prepacked weights
  char* base = (char*)d_ws;
  size_t o = 0;
  unsigned short* Wb1 = (unsigned short*)(base + o); o += ((size_t)512 * 128 * 2 + 255) & ~(size_t)255; // [512][128]
  unsigned short* Wb2 = (unsigned short*)(base + o); o += ((size_t)256 * 512 * 2 + 255) & ~(size_t)255; // [256][512]
  unsigned short* W2h = (unsigned short*)(base + o); o += ((size_t)128 * 128 * 2 + 255) & ~(size_t)255; // [128][128]
  unsigned short* W2l = (unsigned short*)(base + o); o += ((size_t)128 * 128 * 2 + 255) & ~(size_t)255;
  char* tb = base + o;   // transient region (phase1 / phase2 overlay)

  size_t a128 = ((size_t)N * 128 * 2 + 255) & ~(size_t)255;   // 12.8 MB unit
  size_t t = 0;
  unsigned short* hb = (unsigned short*)(tb + t); t += a128;
  unsigned short* x2h = (unsigned short*)(tb + t); t += a128;
  unsigned short* x2l = (unsigned short*)(tb + t); t += a128;
  float2* aSp = (float2*)(tb + t); t += ((size_t)N * 8 + 255) & ~(size_t)255;
  float2* aDp = (float2*)(tb + t); t += ((size_t)N * 8 + 255) & ~(size_t)255;
  int* cnt  = (int*)(tb + t); t += ((size_t)N * 4 + 255) & ~(size_t)255;
  int* offs = (int*)(tb + t); t += ((size_t)(N + 1) * 4 + 255) & ~(size_t)255;
  int* scanws = (int*)(tb + t); t += ((size_t)512 * 4 + 255) & ~(size_t)255;  // psum[256]+flag[256]
  unsigned short* rank = (unsigned short*)(tb + t); t += ((size_t)E * 2 + 255) & ~(size_t)255;
  int* csr  = (int*)(tb + t); t += ((size_t)E * 4 + 255) & ~(size_t)255;
  // phase 2 (MLP head; emb already in d_out) overlays:
  //   embb (bf16 emb copy, written by agg2)  -> x2h region [a128, 2*a128)
  //   z1b (N*512 bf16, m128#1 out)           -> [2*a128, 2*a128+51.2MB)  (x2l.. dead)
  //   z2b (N*256 bf16, m128#2 out)           -> [0, 25.6MB)  (hb+embb dead by then)
  unsigned short* embb = x2h;
  unsigned short* z1b = (unsigned short*)(tb + 2 * a128);
  unsigned short* z2b = (unsigned short*)tb;

  const int* esrc = ei;
  const int* edst = ei + E;

  int eb = (E + 255) / 256;
  int sb = (N + 256) / 256;
  int nb4 = (N + 3) / 4;
  int mtb = (N + 127) / 128;
  int mtb64 = (N + 63) / 64;

  // prep: zero degree counters (canonical symbol) + weight prepack + scan flags
  GNNModel_general_12077448036407_kernel<<<(N + 255) / 256, 256, 0, stream>>>(cnt, N);
  wpack3_kernel<<<512, 256, 0, stream>>>(lw1, Wb1, lw2, Wb2, W2, W2h, W2l, scanws);

  // F1: layer-1 GEMM (x @ W1 -> hb) overlapped with rank (atomic degree+rank)
  gr_fused_kernel<<<mtb + eb, 256, 0, stream>>>(x, W1, hb, N, mtb, edst, cnt, rank, E);

  // single-launch chained scan (replaces scan1/scan2/scan3)
  scanc_kernel<<<sb, 256, 0, stream>>>(cnt, offs, scanws, N);

  // F2: alphas layer-1 overlapped with CSR place
  pa_fused_kernel<<<nb4 + eb, 256, 0, stream>>>(hb, as1, ad1, aSp, aDp, N, nb4,
                                                esrc, edst, rank, offs, csr, E);

  // GAT layer 1 aggregation -> x2 (hi/lo bf16 prepack for tg2m)
  aggregate_kernel<<<nb4, 256, 0, stream>>>(hb, aSp, aDp, csr, offs, b1,
                                            (float*)0, x2h, x2l, N);

  // GAT layer 2 GEMM (3-term split-precision MFMA) + fused alphas2
  tg2m_kernel<<<mtb64, 256, 0, stream>>>(x2h, x2l, W2h, W2l, as2, ad2, hb, aSp, aDp, N);

  // GAT layer 2 aggregation -> emb (f32 output) + embb (bf16 copy for MLP)
  aggregate_kernel<<<nb4, 256, 0, stream>>>(hb, aSp, aDp, csr, offs, b2,
                                            emb, embb, (unsigned short*)0, N);

  // MLP head: 128 -> 512 -> 256 -> 16 (bf16 MFMA, 128x128 tiles, XCD-chunked)
  int qx = mtb >> 3, rx = mtb & 7;
  int spx = qx + (rx ? 1 : 0);
  m128_kernel<<<dim3(8, spx * 4), 256, 0, stream>>>(embb, Wb1, lb1, z1b,
                                                    N, 128, 512, 1, 1, 1, mtb, 2);
  m128_kernel<<<dim3(8, spx * 2), 256, 0, stream>>>(z1b, Wb2, lb2, z2b,
                                                    N, 512, 256, 1, 1, 1, mtb, 1);
  lgemm_kernel<<<mtb64, 256, 0, stream>>>(z2b, lw3, lb3, logits, N, 256);
}

// Round 8
// 439.584 us; speedup vs baseline: 1.5446x; 1.5446x over previous
//
#include <hip/hip_runtime.h>

typedef __bf16 bf16f __attribute__((ext_vector_type(8)));
typedef float  f32x4 __attribute__((ext_vector_type(4)));

__device__ __forceinline__ float bf2f(unsigned short u) {
  union { unsigned int u; float f; } v;
  v.u = ((unsigned int)u) << 16;
  return v.f;
}
__device__ __forceinline__ unsigned short f2bf(float f) {
  union { float f; unsigned int u; } v; v.f = f;
  unsigned int r = v.u + 0x7FFFu + ((v.u >> 16) & 1u);
  return (unsigned short)(r >> 16);
}
// exact unpack of packed bf16 pair (no rounding involved)
__device__ __forceinline__ float bflo(unsigned int w) {
  union { unsigned int u; float f; } v; v.u = w << 16; return v.f;
}
__device__ __forceinline__ float bfhi(unsigned int w) {
  union { unsigned int u; float f; } v; v.u = w & 0xFFFF0000u; return v.f;
}

// zero the degree counters (canonical kernel symbol kept here)
__global__ void GNNModel_general_12077448036407_kernel(int* cnt, int ncnt) {
  int i = blockIdx.x * blockDim.x + threadIdx.x;
  if (i < ncnt) cnt[i] = 0;
}

// ---- weight prepack: lw1/lw2 -> bf16 [Nt][K]; W2 -> hi/lo bf16 [Nt][K] -----
__global__ void wpack3_kernel(const float* __restrict__ lw1, unsigned short* __restrict__ Wb1,
                              const float* __restrict__ lw2, unsigned short* __restrict__ Wb2,
                              const float* __restrict__ W2, unsigned short* __restrict__ W2h,
                              unsigned short* __restrict__ W2l) {
  int i = blockIdx.x * blockDim.x + threadIdx.x;
  if (i < 512 * 128) {             // Wb1[n][k], n<512, k<128; lw1 is [128][512]
    int n = i >> 7, k = i & 127;
    Wb1[i] = f2bf(lw1[(size_t)k * 512 + n]);
  }
  if (i < 256 * 512) {             // Wb2[n][k], n<256, k<512; lw2 is [512][256]
    int n = i >> 9, k = i & 511;
    Wb2[i] = f2bf(lw2[(size_t)k * 256 + n]);
  }
  if (i < 128 * 128) {             // W2h/W2l[n][k]; W2 is [128][128]
    int n = i >> 7, k = i & 127;
    float w = W2[(size_t)k * 128 + n];
    unsigned short h = f2bf(w);
    W2h[i] = h;
    W2l[i] = f2bf(w - bf2f(h));
  }
}

// ---------------- F1: layer-1 GEMM (blocks [0,gblocks)) || rank (rest) ------
// tgemm1: hb[M,128] = bf16(x[M,64] @ W1[64,128]); rank: degree count + rank.
// The rank blocks are atomic-latency-bound (VALU ~0%); co-residency with the
// compute-bound GEMM blocks hides the GEMM entirely under the atomic pass.
// NOTE: keep this epilogue minimal — fusing alphas here (round 4) pushed the
// critical dispatch 80->93 us; alphas1 rides the place launch instead.
__launch_bounds__(256)
__global__ void gr_fused_kernel(const float* __restrict__ x, const float* __restrict__ W1,
                                unsigned short* __restrict__ hb, int M, int gblocks,
                                const int* __restrict__ dst, int* __restrict__ cnt,
                                unsigned short* __restrict__ rank, int E) {
  __shared__ float As[16][132];
  __shared__ float Bs[16][136];
  int bid = blockIdx.x;
  int t = threadIdx.x;

  if (bid >= gblocks) {
    int e = (bid - gblocks) * 256 + t;
    if (e < E) {
      int r = atomicAdd(&cnt[dst[e]], 1);
      rank[e] = (unsigned short)r;
    }
    return;
  }

  // ---- tgemm specialized: K=64, Nt=128, A f32, C bf16, no bias, no relu ----
  int tx = t & 15, ty = t >> 4;
  int m0 = bid * 128;

  float acc[8][8];
#pragma unroll
  for (int i = 0; i < 8; i++)
#pragma unroll
    for (int j = 0; j < 8; j++) acc[i][j] = 0.0f;

  int arow = t >> 1;
  int akc  = (t & 1) * 8;
  int bkk  = t >> 4;
  int bnn  = (t & 15) * 8;
  int gm = m0 + arow;

  for (int k0 = 0; k0 < 64; k0 += 16) {
    float av[8];
    if (gm < M) {
      const float* Af = x + (size_t)gm * 64 + k0 + akc;
      float4 r0 = *(const float4*)Af;
      float4 r1 = *(const float4*)(Af + 4);
      av[0] = r0.x; av[1] = r0.y; av[2] = r0.z; av[3] = r0.w;
      av[4] = r1.x; av[5] = r1.y; av[6] = r1.z; av[7] = r1.w;
    } else {
#pragma unroll
      for (int j = 0; j < 8; j++) av[j] = 0.0f;
    }
#pragma unroll
    for (int j = 0; j < 8; j++) As[akc + j][arow] = av[j];

    const float* bp = W1 + (size_t)(k0 + bkk) * 128 + bnn;
    float4 b0 = *(const float4*)bp;
    float4 b1 = *(const float4*)(bp + 4);
    *(float4*)&Bs[bkk][bnn]     = b0;
    *(float4*)&Bs[bkk][bnn + 4] = b1;

    __syncthreads();

#pragma unroll 4
    for (int kk = 0; kk < 16; kk++) {
      float a[8], b[8];
      *(float4*)&a[0] = *(const float4*)&As[kk][ty * 8];
      *(float4*)&a[4] = *(const float4*)&As[kk][ty * 8 + 4];
      *(float4*)&b[0] = *(const float4*)&Bs[kk][tx * 8];
      *(float4*)&b[4] = *(const float4*)&Bs[kk][tx * 8 + 4];
#pragma unroll
      for (int i = 0; i < 8; i++)
#pragma unroll
        for (int j = 0; j < 8; j++)
          acc[i][j] = fmaf(a[i], b[j], acc[i][j]);
    }
    __syncthreads();
  }

#pragma unroll
  for (int i = 0; i < 8; i++) {
    int m = m0 + ty * 8 + i;
    if (m >= M) continue;
    unsigned short* Cp = hb + (size_t)m * 128 + tx * 8;
    uint4 pk;
    pk.x = (unsigned int)f2bf(acc[i][0]) | ((unsigned int)f2bf(acc[i][1]) << 16);
    pk.y = (unsigned int)f2bf(acc[i][2]) | ((unsigned int)f2bf(acc[i][3]) << 16);
    pk.z = (unsigned int)f2bf(acc[i][4]) | ((unsigned int)f2bf(acc[i][5]) << 16);
    pk.w = (unsigned int)f2bf(acc[i][6]) | ((unsigned int)f2bf(acc[i][7]) << 16);
    *(uint4*)Cp = pk;
  }
}

// ---------------- CSR scan chain (3 launches, ~7 us total) -------------------
// NOTE: single-launch chained scan (round 7) was 243 us — 196 serial
// cross-XCD atomic hops at ~1.2 us each. Never serialize blocks on MI355X.
__global__ void scan1_kernel(const int* __restrict__ cnt, int* __restrict__ offs,
                             int* __restrict__ bsum, int M) {
  __shared__ int sh[256];
  int t = threadIdx.x;
  int i = blockIdx.x * 256 + t;
  int v = (i < M) ? cnt[i] : 0;
  sh[t] = v;
  __syncthreads();
  for (int off = 1; off < 256; off <<= 1) {
    int u = (t >= off) ? sh[t - off] : 0;
    __syncthreads();
    sh[t] += u;
    __syncthreads();
  }
  if (i <= M) offs[i] = sh[t] - v;
  if (t == 255) bsum[blockIdx.x] = sh[255];
}

__global__ void scan2_kernel(int* __restrict__ bsum, int NB) {
  __shared__ int sh[256];
  int t = threadIdx.x;
  int v = (t < NB) ? bsum[t] : 0;
  sh[t] = v;
  __syncthreads();
  for (int off = 1; off < 256; off <<= 1) {
    int u = (t >= off) ? sh[t - off] : 0;
    __syncthreads();
    sh[t] += u;
    __syncthreads();
  }
  if (t < NB) bsum[t] = sh[t] - v;
}

__global__ void scan3_kernel(int* __restrict__ offs, const int* __restrict__ bsum, int M) {
  int i = blockIdx.x * 256 + threadIdx.x;
  if (i <= M) offs[i] += bsum[i >> 8];
}

// ---------------- F2: alphas layer1 (blocks [0,ablocks)) || place (rest) ----
__global__ void pa_fused_kernel(const unsigned short* __restrict__ hb,
                                const float* __restrict__ a_src,
                                const float* __restrict__ a_dst,
                                float2* __restrict__ aSp, float2* __restrict__ aDp,
                                int M, int ablocks,
                                const int* __restrict__ src, const int* __restrict__ dstp,
                                const unsigned short* __restrict__ rank,
                                const int* __restrict__ offs, int* __restrict__ csr, int E) {
  int bid = blockIdx.x;
  int t = threadIdx.x;

  if (bid >= ablocks) {
    int e = (bid - ablocks) * 256 + t;
    if (e < E) {
      int p = offs[dstp[e]] + (int)rank[e];
      __builtin_nontemporal_store(src[e], &csr[p]);
    }
    return;
  }

  int gw = (bid * 256 + t) >> 6;
  int lane = t & 63;
  if (gw >= M) return;
  float h0 = bf2f(hb[(size_t)gw * 128 + lane]);
  float h1 = bf2f(hb[(size_t)gw * 128 + 64 + lane]);
  float as0 = h0 * a_src[lane];
  float as1 = h1 * a_src[64 + lane];
  float ad0 = h0 * a_dst[lane];
  float ad1 = h1 * a_dst[64 + lane];
  for (int o = 32; o; o >>= 1) {
    as0 += __shfl_xor(as0, o);
    as1 += __shfl_xor(as1, o);
    ad0 += __shfl_xor(ad0, o);
    ad1 += __shfl_xor(ad1, o);
  }
  if (lane == 0) {
    aSp[gw] = make_float2(as0, as1);
    aDp[gw] = make_float2(ad0, ad1);
  }
}

// ---------------- MFMA bf16 GEMM, m97 structure (MLP path) -------------------
// 128x128 tile, BK=32, 4 waves (2x2), 4x4 fragments of 16x16x32 per wave.
// B prepacked bf16 [Nt][K] staged via global_load_lds width=16; A direct-to-LDS
// when bf16, reg-staged f32->bf16 when f32. XCD-chunked work map (blockIdx.x =
// XCD = linear id % 8) so each A panel is fetched into exactly one XCD L2.
// Epilogue: two-pass LDS re-layout then cooperative uint4 stores (full 128B
// HBM lines; direct 2B stores caused 2.4x write amplification).
__launch_bounds__(256)
__global__ void m128_kernel(const void* __restrict__ A,
                            const unsigned short* __restrict__ Bw,
                            const float* __restrict__ bias, void* __restrict__ C,
                            int M, int K, int Nt, int aBF, int cBF, int relu,
                            int mtiles, int lgNB) {
  __shared__ unsigned short sh[8704];            // staging 16 KB / epilogue 128x68
  unsigned short* As = sh;                       // 128*32
  unsigned short* Bs = sh + 4096;                // 128*32
  int tid = threadIdx.x;
  int wid = tid >> 6, lane = tid & 63;
  int lm = lane & 15, quad = lane >> 4;
  int wr = wid >> 1, wc = wid & 1;

  // ---- XCD-chunked (m,n) tile assignment ----
  int xcd = blockIdx.x;                          // == linear dispatch id % 8
  int slot = blockIdx.y;
  int qm = mtiles >> 3, rm = mtiles & 7;
  int cntm = qm + (xcd < rm);
  int mstart = xcd * qm + (xcd < rm ? xcd : rm);
  if (slot >= (cntm << lgNB)) return;
  int NBm1 = (1 << lgNB) - 1;
  int m0 = (mstart + (slot >> lgNB)) * 128;
  int n0 = (slot & NBm1) * 128;

  f32x4 acc[4][4];
#pragma unroll
  for (int mi = 0; mi < 4; mi++)
#pragma unroll
    for (int ni = 0; ni < 4; ni++)
#pragma unroll
      for (int i = 0; i < 4; i++) acc[mi][ni][i] = 0.0f;

  // staging ids
  int c0 = (wid << 6) + lane;       // chunk ids for direct-to-LDS 16B loads
  int c1 = c0 + 256;
  int srow = tid >> 1;              // reg-stage (aBF=0): row 0..127
  int skc  = (tid & 1) << 4;        // k sub-offset 0/16 (16 floats each)

  for (int k0 = 0; k0 < K; k0 += 32) {
    // ---- B tile: 128 n-rows x 32 k, linear LDS, 2x global_load_lds / thread
    {
      const unsigned short* g0 = Bw + (size_t)(n0 + (c0 >> 2)) * K + k0 + ((c0 & 3) << 3);
      __builtin_amdgcn_global_load_lds((const __attribute__((address_space(1))) void*)g0,
                                       (__attribute__((address_space(3))) void*)(Bs + (wid << 9)),
                                       16, 0, 0);
      const unsigned short* g1 = Bw + (size_t)(n0 + (c1 >> 2)) * K + k0 + ((c1 & 3) << 3);
      __builtin_amdgcn_global_load_lds((const __attribute__((address_space(1))) void*)g1,
                                       (__attribute__((address_space(3))) void*)(Bs + 2048 + (wid << 9)),
                                       16, 0, 0);
    }
    // ---- A tile
    if (aBF) {
      int r0 = m0 + (c0 >> 2); if (r0 > M - 1) r0 = M - 1;   // clamp tail (rows >= M never written)
      const unsigned short* g0 = (const unsigned short*)A + (size_t)r0 * K + k0 + ((c0 & 3) << 3);
      __builtin_amdgcn_global_load_lds((const __attribute__((address_space(1))) void*)g0,
                                       (__attribute__((address_space(3))) void*)(As + (wid << 9)),
                                       16, 0, 0);
      int r1 = m0 + (c1 >> 2); if (r1 > M - 1) r1 = M - 1;
      const unsigned short* g1 = (const unsigned short*)A + (size_t)r1 * K + k0 + ((c1 & 3) << 3);
      __builtin_amdgcn_global_load_lds((const __attribute__((address_space(1))) void*)g1,
                                       (__attribute__((address_space(3))) void*)(As + 2048 + (wid << 9)),
                                       16, 0, 0);
    } else {
      int gm = m0 + srow;
      uint4 p0, p1;
      if (gm < M) {
        const float* Af = (const float*)A + (size_t)gm * K + k0 + skc;
        float4 r0 = *(const float4*)Af;
        float4 r1 = *(const float4*)(Af + 4);
        float4 r2 = *(const float4*)(Af + 8);
        float4 r3 = *(const float4*)(Af + 12);
        p0.x = (unsigned int)f2bf(r0.x) | ((unsigned int)f2bf(r0.y) << 16);
        p0.y = (unsigned int)f2bf(r0.z) | ((unsigned int)f2bf(r0.w) << 16);
        p0.z = (unsigned int)f2bf(r1.x) | ((unsigned int)f2bf(r1.y) << 16);
        p0.w = (unsigned int)f2bf(r1.z) | ((unsigned int)f2bf(r1.w) << 16);
        p1.x = (unsigned int)f2bf(r2.x) | ((unsigned int)f2bf(r2.y) << 16);
        p1.y = (unsigned int)f2bf(r2.z) | ((unsigned int)f2bf(r2.w) << 16);
        p1.z = (unsigned int)f2bf(r3.x) | ((unsigned int)f2bf(r3.y) << 16);
        p1.w = (unsigned int)f2bf(r3.z) | ((unsigned int)f2bf(r3.w) << 16);
      } else {
        p0.x = p0.y = p0.z = p0.w = 0u;
        p1.x = p1.y = p1.z = p1.w = 0u;
      }
      *(uint4*)&As[srow * 32 + skc] = p0;
      *(uint4*)&As[srow * 32 + skc + 8] = p1;
    }
    __syncthreads();

    bf16f afr[4], bfr[4];
#pragma unroll
    for (int mi = 0; mi < 4; mi++)
      afr[mi] = *(const bf16f*)&As[(wr * 64 + mi * 16 + lm) * 32 + quad * 8];
#pragma unroll
    for (int ni = 0; ni < 4; ni++)
      bfr[ni] = *(const bf16f*)&Bs[(wc * 64 + ni * 16 + lm) * 32 + quad * 8];
#pragma unroll
    for (int mi = 0; mi < 4; mi++)
#pragma unroll
      for (int ni = 0; ni < 4; ni++)
        acc[mi][ni] = __builtin_amdgcn_mfma_f32_16x16x32_bf16(afr[mi], bfr[ni], acc[mi][ni], 0, 0, 0);
    __syncthreads();
  }

  if (cBF) {
    // ---- two-pass LDS-staged coalesced bf16 epilogue ----
#pragma unroll
    for (int p = 0; p < 2; p++) {
      __syncthreads();
      if (wc == p) {
#pragma unroll
        for (int ni = 0; ni < 4; ni++) {
          int colb = ni * 16 + lm;                      // 0..63 within pass
          float bv = (bias != 0) ? bias[n0 + p * 64 + colb] : 0.0f;
#pragma unroll
          for (int mi = 0; mi < 4; mi++) {
#pragma unroll
            for (int i = 0; i < 4; i++) {
              int rowb = wr * 64 + mi * 16 + quad * 4 + i;
              float v = acc[mi][ni][i] + bv;
              if (relu) v = fmaxf(v, 0.0f);
              sh[rowb * 68 + colb] = f2bf(v);
            }
          }
        }
      }
      __syncthreads();
#pragma unroll
      for (int sweep = 0; sweep < 4; sweep++) {
        int rowb = (tid >> 3) + 32 * sweep;
        int seg = tid & 7;
        int grow = m0 + rowb;
        if (grow < M) {
          uint4 val = *(const uint4*)&sh[rowb * 68 + seg * 8];
          *(uint4*)((unsigned short*)C + (size_t)grow * Nt + n0 + p * 64 + seg * 8) = val;
        }
      }
    }
  } else {
    // f32 fallback (unused in current launches)
#pragma unroll
    for (int ni = 0; ni < 4; ni++) {
      int col = n0 + wc * 64 + ni * 16 + lm;
      float bv = (bias != 0) ? bias[col] : 0.0f;
#pragma unroll
      for (int mi = 0; mi < 4; mi++) {
#pragma unroll
        for (int i = 0; i < 4; i++) {
          int row = m0 + wr * 64 + mi * 16 + quad * 4 + i;
          if (row < M) {
            float v = acc[mi][ni][i] + bv;
            if (relu) v = fmaxf(v, 0.0f);
            ((float*)C)[(size_t)row * Nt + col] = v;
          }
        }
      }
    }
  }
}

// ---------------- layer-2 GEMM: 3-term split-precision bf16 MFMA ------------
// hb[M,128] = bf16(x2[M,128] @ W2[128,128]), f32-class accuracy.
// A comes prepacked hi/lo bf16 from aggregate1 (x2h/x2l); all tiles stage via
// global_load_lds. BM=64, 4 waves 2x2, fused alphas2.
__launch_bounds__(256)
__global__ void tg2m_kernel(const unsigned short* __restrict__ Ahp,
                            const unsigned short* __restrict__ Alp,
                            const unsigned short* __restrict__ Bh,
                            const unsigned short* __restrict__ Bl,
                            const float* __restrict__ a_src, const float* __restrict__ a_dst,
                            unsigned short* __restrict__ hb,
                            float2* __restrict__ aSp, float2* __restrict__ aDp,
                            int M) {
  __shared__ unsigned short sh[12288];          // 24 KB
  unsigned short* Ah = sh;                      // 64*32
  unsigned short* Al = sh + 2048;
  unsigned short* BH = sh + 4096;               // 128*32
  unsigned short* BL = sh + 8192;
  const int K = 128;
  int tid = threadIdx.x;
  int wid = tid >> 6, lane = tid & 63;
  int lm = lane & 15, quad = lane >> 4;
  int wr = wid >> 1, wc = wid & 1;
  int m0 = blockIdx.x * 64;

  f32x4 acc[2][4];
#pragma unroll
  for (int mi = 0; mi < 2; mi++)
#pragma unroll
    for (int ni = 0; ni < 4; ni++)
#pragma unroll
      for (int i = 0; i < 4; i++) acc[mi][ni][i] = 0.0f;

  int c0 = (wid << 6) + lane, c1 = c0 + 256;

  for (int k0 = 0; k0 < K; k0 += 32) {
    // B hi/lo tiles: 128 n-rows x 32 k each, direct-to-LDS
    {
      const unsigned short* g0 = Bh + (size_t)(c0 >> 2) * K + k0 + ((c0 & 3) << 3);
      __builtin_amdgcn_global_load_lds((const __attribute__((address_space(1))) void*)g0,
                                       (__attribute__((address_space(3))) void*)(BH + (wid << 9)),
                                       16, 0, 0);
      const unsigned short* g1 = Bh + (size_t)(c1 >> 2) * K + k0 + ((c1 & 3) << 3);
      __builtin_amdgcn_global_load_lds((const __attribute__((address_space(1))) void*)g1,
                                       (__attribute__((address_space(3))) void*)(BH + 2048 + (wid << 9)),
                                       16, 0, 0);
      const unsigned short* g2 = Bl + (size_t)(c0 >> 2) * K + k0 + ((c0 & 3) << 3);
      __builtin_amdgcn_global_load_lds((const __attribute__((address_space(1))) void*)g2,
                                       (__attribute__((address_space(3))) void*)(BL + (wid << 9)),
                                       16, 0, 0);
      const unsigned short* g3 = Bl + (size_t)(c1 >> 2) * K + k0 + ((c1 & 3) << 3);
      __builtin_amdgcn_global_load_lds((const __attribute__((address_space(1))) void*)g3,
                                       (__attribute__((address_space(3))) void*)(BL + 2048 + (wid << 9)),
                                       16, 0, 0);
    }
    // A hi/lo tiles: 64 rows x 32 k, direct-to-LDS (256 chunks = whole tile)
    {
      int r0 = m0 + (c0 >> 2); if (r0 > M - 1) r0 = M - 1;   // tail clamp
      const unsigned short* g0 = Ahp + (size_t)r0 * K + k0 + ((c0 & 3) << 3);
      __builtin_amdgcn_global_load_lds((const __attribute__((address_space(1))) void*)g0,
                                       (__attribute__((address_space(3))) void*)(Ah + (wid << 9)),
                                       16, 0, 0);
      const unsigned short* g1 = Alp + (size_t)r0 * K + k0 + ((c0 & 3) << 3);
      __builtin_amdgcn_global_load_lds((const __attribute__((address_space(1))) void*)g1,
                                       (__attribute__((address_space(3))) void*)(Al + (wid << 9)),
                                       16, 0, 0);
    }
    __syncthreads();

    bf16f ahf[2], alf[2];
#pragma unroll
    for (int mi = 0; mi < 2; mi++) {
      ahf[mi] = *(const bf16f*)&Ah[(wr * 32 + mi * 16 + lm) * 32 + quad * 8];
      alf[mi] = *(const bf16f*)&Al[(wr * 32 + mi * 16 + lm) * 32 + quad * 8];
    }
#pragma unroll
    for (int ni = 0; ni < 4; ni++) {
      bf16f vbh = *(const bf16f*)&BH[(wc * 64 + ni * 16 + lm) * 32 + quad * 8];
      bf16f vbl = *(const bf16f*)&BL[(wc * 64 + ni * 16 + lm) * 32 + quad * 8];
#pragma unroll
      for (int mi = 0; mi < 2; mi++) {
        acc[mi][ni] = __builtin_amdgcn_mfma_f32_16x16x32_bf16(ahf[mi], vbh, acc[mi][ni], 0, 0, 0);
        acc[mi][ni] = __builtin_amdgcn_mfma_f32_16x16x32_bf16(alf[mi], vbh, acc[mi][ni], 0, 0, 0);
        acc[mi][ni] = __builtin_amdgcn_mfma_f32_16x16x32_bf16(ahf[mi], vbl, acc[mi][ni], 0, 0, 0);
      }
    }
    __syncthreads();
  }

  // ---- epilogue: two col-passes; coalesced hb stores + fused alphas --------
  float ps[2], pd[2];
#pragma unroll
  for (int p = 0; p < 2; p++) {
    __syncthreads();
    if (wc == p) {
#pragma unroll
      for (int ni = 0; ni < 4; ni++) {
        int colb = ni * 16 + lm;
#pragma unroll
        for (int mi = 0; mi < 2; mi++)
#pragma unroll
          for (int i = 0; i < 4; i++) {
            int rowb = wr * 32 + mi * 16 + quad * 4 + i;
            sh[rowb * 72 + colb] = f2bf(acc[mi][ni][i]);
          }
      }
    }
    __syncthreads();
    // coalesced store: 64 rows x 64 cols (8 x uint4 per row)
#pragma unroll
    for (int sweep = 0; sweep < 2; sweep++) {
      int rowb = (tid >> 3) + 32 * sweep;
      int seg = tid & 7;
      int grow = m0 + rowb;
      if (grow < M) {
        uint4 val = *(const uint4*)&sh[rowb * 72 + seg * 8];
        *(uint4*)(hb + (size_t)grow * 128 + p * 64 + seg * 8) = val;
      }
    }
    // alphas partials for head p: 4 threads/row x 16 cols
    {
      int row = tid >> 2, sg = tid & 3;
      const float* As_ = a_src + p * 64 + sg * 16;
      const float* Ad_ = a_dst + p * 64 + sg * 16;
      float s = 0.0f, d = 0.0f;
#pragma unroll
      for (int c8 = 0; c8 < 2; c8++) {
        uint4 rv = *(const uint4*)&sh[row * 72 + sg * 16 + c8 * 8];
        const float* Ap_ = As_ + c8 * 8;
        const float* Dp_ = Ad_ + c8 * 8;
        float hv[8];
        hv[0] = bflo(rv.x); hv[1] = bfhi(rv.x);
        hv[2] = bflo(rv.y); hv[3] = bfhi(rv.y);
        hv[4] = bflo(rv.z); hv[5] = bfhi(rv.z);
        hv[6] = bflo(rv.w); hv[7] = bfhi(rv.w);
#pragma unroll
        for (int j = 0; j < 8; j++) {
          s = fmaf(hv[j], Ap_[j], s);
          d = fmaf(hv[j], Dp_[j], d);
        }
      }
      s += __shfl_xor(s, 1); s += __shfl_xor(s, 2);
      d += __shfl_xor(d, 1); d += __shfl_xor(d, 2);
      ps[p] = s; pd[p] = d;
    }
  }
  {
    int row = tid >> 2, sg = tid & 3;
    int m = m0 + row;
    if (sg == 0 && m < M) {
      aSp[m] = make_float2(ps[0], ps[1]);
      aDp[m] = make_float2(pd[0], pd[1]);
    }
  }
}

// ---------------- MFMA logits GEMM: C[M,16] = A[M,K]@W[K,16] + bias ----------
__launch_bounds__(256)
__global__ void lgemm_kernel(const unsigned short* __restrict__ A,
                             const float* __restrict__ W,
                             const float* __restrict__ bias, float* __restrict__ C,
                             int M, int K) {
  __shared__ unsigned short Bt[16 * 264];
  int tid = threadIdx.x;
  int wave = tid >> 6, lane = tid & 63;
  int lm = lane & 15, quad = lane >> 4;
  int m0 = blockIdx.x * 64;

  // stage W (K x 16 f32) -> Bt[n][k] bf16
  for (int f0 = tid * 4; f0 < K * 16; f0 += 1024) {
    float4 w4 = *(const float4*)(W + f0);
    int k = f0 >> 4, n = f0 & 15;
    Bt[(n + 0) * 264 + k] = f2bf(w4.x);
    Bt[(n + 1) * 264 + k] = f2bf(w4.y);
    Bt[(n + 2) * 264 + k] = f2bf(w4.z);
    Bt[(n + 3) * 264 + k] = f2bf(w4.w);
  }
  __syncthreads();

  f32x4 acc;
#pragma unroll
  for (int i = 0; i < 4; i++) acc[i] = 0.0f;

  int m = m0 + wave * 16 + lm;                 // A-operand row for this lane
  const unsigned short* Ap = A + (size_t)m * K;

  for (int k0 = 0; k0 < K; k0 += 32) {
    bf16f af;
#pragma unroll
    for (int j = 0; j < 8; j++) af[j] = (__bf16)0.0f;
    if (m < M) af = *(const bf16f*)(Ap + k0 + quad * 8);
    bf16f bfv = *(const bf16f*)&Bt[lm * 264 + k0 + quad * 8];
    acc = __builtin_amdgcn_mfma_f32_16x16x32_bf16(af, bfv, acc, 0, 0, 0);
  }

  float bv = bias[lm];
#pragma unroll
  for (int i = 0; i < 4; i++) {
    int row = m0 + wave * 16 + quad * 4 + i;
    if (row < M) C[(size_t)row * 16 + lm] = acc[i] + bv;
  }
}

// ---------------- per-node softmax aggregation (bf16 gather) -----------------
// Epilogue writes any of: f32 out, bf16-hi out, bf16-lo out (nullable).
__global__ void aggregate_kernel(const unsigned short* __restrict__ hb,
                                 const float2* __restrict__ aSp,
                                 const float2* __restrict__ aDp,
                                 const int* __restrict__ csr_src, const int* __restrict__ offs,
                                 const float* __restrict__ bias,
                                 float* __restrict__ outf,
                                 unsigned short* __restrict__ outh,
                                 unsigned short* __restrict__ outl, int M) {
  int n = (blockIdx.x * blockDim.x + threadIdx.x) >> 6;
  int lane = threadIdx.x & 63;
  if (n >= M) return;
  int g = lane >> 4;
  int q = lane & 15;
  int h0sel = (q < 8);

  float2 adn = aDp[n];
  float2 asn = aSp[n];
  float e0 = asn.x + adn.x; e0 = (e0 > 0.0f) ? e0 : 0.2f * e0;   // leaky_relu 0.2
  float e1 = asn.y + adn.y; e1 = (e1 > 0.0f) ? e1 : 0.2f * e1;
  float ws0 = expf(e0), ws1 = expf(e1);
  float wself = h0sel ? ws0 : ws1;

  float acc[8];
  if (g == 0) {
    uint4 rv = *(const uint4*)(hb + (size_t)n * 128 + q * 8);
    acc[0] = wself * bflo(rv.x); acc[1] = wself * bfhi(rv.x);
    acc[2] = wself * bflo(rv.y); acc[3] = wself * bfhi(rv.y);
    acc[4] = wself * bflo(rv.z); acc[5] = wself * bfhi(rv.z);
    acc[6] = wself * bflo(rv.w); acc[7] = wself * bfhi(rv.w);
  } else {
#pragma unroll
    for (int i = 0; i < 8; i++) acc[i] = 0.0f;
  }

  float lp0 = 0.0f, lp1 = 0.0f;
  int rs = offs[n], re = offs[n + 1];
  for (int base = rs; base < re; base += 64) {
    int cnt = re - base; if (cnt > 64) cnt = 64;
    int s = 0; float w0 = 0.0f, w1 = 0.0f;
    if (lane < cnt) {
      s = csr_src[base + lane];
      float2 a = aSp[s];
      float f0 = a.x + adn.x; f0 = (f0 > 0.0f) ? f0 : 0.2f * f0;
      float f1 = a.y + adn.y; f1 = (f1 > 0.0f) ? f1 : 0.2f * f1;
      w0 = expf(f0); w1 = expf(f1);
      lp0 += w0; lp1 += w1;
    }
    int jmax = (cnt + 3) >> 2;
#pragma unroll 8
    for (int j = 0; j < jmax; j++) {
      int el = 4 * j + g;
      int sj  = __shfl(s, el);
      float w0j = __shfl(w0, el);
      float w1j = __shfl(w1, el);
      float wj = h0sel ? w0j : w1j;
      uint4 rv = *(const uint4*)(hb + (size_t)sj * 128 + q * 8);
      acc[0] = fmaf(wj, bflo(rv.x), acc[0]);
      acc[1] = fmaf(wj, bfhi(rv.x), acc[1]);
      acc[2] = fmaf(wj, bflo(rv.y), acc[2]);
      acc[3] = fmaf(wj, bfhi(rv.y), acc[3]);
      acc[4] = fmaf(wj, bflo(rv.z), acc[4]);
      acc[5] = fmaf(wj, bfhi(rv.z), acc[5]);
      acc[6] = fmaf(wj, bflo(rv.w), acc[6]);
      acc[7] = fmaf(wj, bfhi(rv.w), acc[7]);
    }
  }
#pragma unroll
  for (int i = 0; i < 8; i++) {
    acc[i] += __shfl_xor(acc[i], 16);
    acc[i] += __shfl_xor(acc[i], 32);
  }
  for (int o = 32; o; o >>= 1) {
    lp0 += __shfl_xor(lp0, o);
    lp1 += __shfl_xor(lp1, o);
  }
  if (g == 0) {
    float linv = 1.0f / ((h0sel ? lp0 + ws0 : lp1 + ws1) + 1e-16f);
    const float* bp = bias + q * 8;
    float v[8];
#pragma unroll
    for (int i = 0; i < 8; i++) v[i] = fmaxf(acc[i] * linv + bp[i], 0.0f);
    if (outf) {
      float4 o0, o1;
      o0.x = v[0]; o0.y = v[1]; o0.z = v[2]; o0.w = v[3];
      o1.x = v[4]; o1.y = v[5]; o1.z = v[6]; o1.w = v[7];
      float* op = outf + (size_t)n * 128 + q * 8;
      *(float4*)op = o0;
      *(float4*)(op + 4) = o1;
    }
    if (outh) {
      unsigned short hh[8];
#pragma unroll
      for (int i = 0; i < 8; i++) hh[i] = f2bf(v[i]);
      uint4 ph;
      ph.x = (unsigned int)hh[0] | ((unsigned int)hh[1] << 16);
      ph.y = (unsigned int)hh[2] | ((unsigned int)hh[3] << 16);
      ph.z = (unsigned int)hh[4] | ((unsigned int)hh[5] << 16);
      ph.w = (unsigned int)hh[6] | ((unsigned int)hh[7] << 16);
      *(uint4*)(outh + (size_t)n * 128 + q * 8) = ph;
      if (outl) {
        unsigned short ll[8];
#pragma unroll
        for (int i = 0; i < 8; i++) ll[i] = f2bf(v[i] - bf2f(hh[i]));
        uint4 pl;
        pl.x = (unsigned int)ll[0] | ((unsigned int)ll[1] << 16);
        pl.y = (unsigned int)ll[2] | ((unsigned int)ll[3] << 16);
        pl.z = (unsigned int)ll[4] | ((unsigned int)ll[5] << 16);
        pl.w = (unsigned int)ll[6] | ((unsigned int)ll[7] << 16);
        *(uint4*)(outl + (size_t)n * 128 + q * 8) = pl;
      }
    }
  }
}

extern "C" void kernel_launch(void* const* d_in, const int* in_sizes, int n_in,
                              void* d_out, int out_size, void* d_ws, size_t ws_size,
                              hipStream_t stream) {
  const int N = in_sizes[0] / 64;   // 50000
  const int E = in_sizes[1] / 2;    // 1,600,000
  const float* x   = (const float*)d_in[0];
  const int*   ei  = (const int*)d_in[1];
  const float* W1  = (const float*)d_in[2];
  const float* as1 = (const float*)d_in[3];
  const float* ad1 = (const float*)d_in[4];
  const float* b1  = (const float*)d_in[5];
  const float* W2  = (const float*)d_in[6];
  const float* as2 = (const float*)d_in[7];
  const float* ad2 = (const float*)d_in[8];
  const float* b2  = (const float*)d_in[9];
  const float* lw1 = (const float*)d_in[10];
  const float* lb1 = (const float*)d_in[11];
  const float* lw2 = (const float*)d_in[12];
  const float* lb2 = (const float*)d_in[13];
  const float* lw3 = (const float*)d_in[14];
  const float* lb3 = (const float*)d_in[15];

  float* emb    = (float*)d_out;                    // N*128 f32
  float* logits = (float*)d_out + (size_t)N * 128;  // N*16 f32

  // ---- workspace layout ----
  // persistent (live across phases): prepacked weights
  char* base = (char*)d_ws;
  size_t o = 0;
  unsigned short* Wb1 = (unsigned short*)(base + o); o += ((size_t)512 * 128 * 2 + 255) & ~(size_t)255; // [512][128]
  unsigned short* Wb2 = (unsigned short*)(base + o); o += ((size_t)256 * 512 * 2 + 255) & ~(size_t)255; // [256][512]
  unsigned short* W2h = (unsigned short*)(base + o); o += ((size_t)128 * 128 * 2 + 255) & ~(size_t)255; // [128][128]
  unsigned short* W2l = (unsigned short*)(base + o); o += ((size_t)128 * 128 * 2 + 255) & ~(size_t)255;
  char* tb = base + o;   // transient region (phase1 / phase2 overlay)

  size_t a128 = ((size_t)N * 128 * 2 + 255) & ~(size_t)255;   // 12.8 MB unit
  size_t t = 0;
  unsigned short* hb = (unsigned short*)(tb + t); t += a128;
  unsigned short* x2h = (unsigned short*)(tb + t); t += a128;
  unsigned short* x2l = (unsigned short*)(tb + t); t += a128;
  float2* aSp = (float2*)(tb + t); t += ((size_t)N * 8 + 255) & ~(size_t)255;
  float2* aDp = (float2*)(tb + t); t += ((size_t)N * 8 + 255) & ~(size_t)255;
  int* cnt  = (int*)(tb + t); t += ((size_t)N * 4 + 255) & ~(size_t)255;
  int* offs = (int*)(tb + t); t += ((size_t)(N + 1) * 4 + 255) & ~(size_t)255;
  int* bsum = (int*)(tb + t); t += ((size_t)256 * 4 + 255) & ~(size_t)255;
  unsigned short* rank = (unsigned short*)(tb + t); t += ((size_t)E * 2 + 255) & ~(size_t)255;
  int* csr  = (int*)(tb + t); t += ((size_t)E * 4 + 255) & ~(size_t)255;
  // phase 2 (MLP head; emb already in d_out) overlays:
  //   embb (bf16 emb copy, written by agg2)  -> x2h region [a128, 2*a128)
  //   z1b (N*512 bf16, m128#1 out)           -> [2*a128, ...)  (x2l.. dead)
  //   z2b (N*256 bf16, m128#2 out)           -> [0, ...)  (hb+embb dead by then)
  unsigned short* embb = x2h;
  unsigned short* z1b = (unsigned short*)(tb + 2 * a128);
  unsigned short* z2b = (unsigned short*)tb;

  const int* esrc = ei;
  const int* edst = ei + E;

  int eb = (E + 255) / 256;
  int sb = (N + 256) / 256;
  int nb4 = (N + 3) / 4;
  int mtb = (N + 127) / 128;
  int mtb64 = (N + 63) / 64;

  // prep: zero degree counters (canonical symbol) + fused weight prepack
  GNNModel_general_12077448036407_kernel<<<(N + 255) / 256, 256, 0, stream>>>(cnt, N);
  wpack3_kernel<<<512, 256, 0, stream>>>(lw1, Wb1, lw2, Wb2, W2, W2h, W2l);

  // F1: layer-1 GEMM (x @ W1 -> hb) overlapped with rank (atomic degree+rank)
  gr_fused_kernel<<<mtb + eb, 256, 0, stream>>>(x, W1, hb, N, mtb, edst, cnt, rank, E);

  // CSR scan chain (3 launches; chained 1-launch variant was 243 us — never again)
  scan1_kernel<<<sb, 256, 0, stream>>>(cnt, offs, bsum, N);
  scan2_kernel<<<1, 256, 0, stream>>>(bsum, sb);
  scan3_kernel<<<sb, 256, 0, stream>>>(offs, bsum, N);

  // F2: alphas layer-1 overlapped with CSR place
  pa_fused_kernel<<<nb4 + eb, 256, 0, stream>>>(hb, as1, ad1, aSp, aDp, N, nb4,
                                                esrc, edst, rank, offs, csr, E);

  // GAT layer 1 aggregation -> x2 (hi/lo bf16 prepack for tg2m)
  aggregate_kernel<<<nb4, 256, 0, stream>>>(hb, aSp, aDp, csr, offs, b1,
                                            (float*)0, x2h, x2l, N);

  // GAT layer 2 GEMM (3-term split-precision MFMA) + fused alphas2
  tg2m_kernel<<<mtb64, 256, 0, stream>>>(x2h, x2l, W2h, W2l, as2, ad2, hb, aSp, aDp, N);

  // GAT layer 2 aggregation -> emb (f32 output) + embb (bf16 copy for MLP)
  aggregate_kernel<<<nb4, 256, 0, stream>>>(hb, aSp, aDp, csr, offs, b2,
                                            emb, embb, (unsigned short*)0, N);

  // MLP head: 128 -> 512 -> 256 -> 16 (bf16 MFMA, 128x128 tiles, XCD-chunked)
  int qx = mtb >> 3, rx = mtb & 7;
  int spx = qx + (rx ? 1 : 0);
  m128_kernel<<<dim3(8, spx * 4), 256, 0, stream>>>(embb, Wb1, lb1, z1b,
                                                    N, 128, 512, 1, 1, 1, mtb, 2);
  m128_kernel<<<dim3(8, spx * 2), 256, 0, stream>>>(z1b, Wb2, lb2, z2b,
                                                    N, 512, 256, 1, 1, 1, mtb, 1);
  lgemm_kernel<<<mtb64, 256, 0, stream>>>(z2b, lw3, lb3, logits, N, 256);
}

// Round 9
// 424.538 us; speedup vs baseline: 1.5993x; 1.0354x over previous
//
#include <hip/hip_runtime.h>

typedef __bf16 bf16f __attribute__((ext_vector_type(8)));
typedef float  f32x4 __attribute__((ext_vector_type(4)));

__device__ __forceinline__ float bf2f(unsigned short u) {
  union { unsigned int u; float f; } v;
  v.u = ((unsigned int)u) << 16;
  return v.f;
}
__device__ __forceinline__ unsigned short f2bf(float f) {
  union { float f; unsigned int u; } v; v.f = f;
  unsigned int r = v.u + 0x7FFFu + ((v.u >> 16) & 1u);
  return (unsigned short)(r >> 16);
}
// exact unpack of packed bf16 pair (no rounding involved)
__device__ __forceinline__ float bflo(unsigned int w) {
  union { unsigned int u; float f; } v; v.u = w << 16; return v.f;
}
__device__ __forceinline__ float bfhi(unsigned int w) {
  union { unsigned int u; float f; } v; v.u = w & 0xFFFF0000u; return v.f;
}

// zero the degree counters (canonical kernel symbol kept here)
__global__ void GNNModel_general_12077448036407_kernel(int* cnt, int ncnt) {
  int i = blockIdx.x * blockDim.x + threadIdx.x;
  if (i < ncnt) cnt[i] = 0;
}

// ---- weight prepack: lw1/lw2 -> bf16 [Nt][K]; W2 -> hi/lo bf16 [Nt][K] -----
__global__ void wpack3_kernel(const float* __restrict__ lw1, unsigned short* __restrict__ Wb1,
                              const float* __restrict__ lw2, unsigned short* __restrict__ Wb2,
                              const float* __restrict__ W2, unsigned short* __restrict__ W2h,
                              unsigned short* __restrict__ W2l) {
  int i = blockIdx.x * blockDim.x + threadIdx.x;
  if (i < 512 * 128) {             // Wb1[n][k], n<512, k<128; lw1 is [128][512]
    int n = i >> 7, k = i & 127;
    Wb1[i] = f2bf(lw1[(size_t)k * 512 + n]);
  }
  if (i < 256 * 512) {             // Wb2[n][k], n<256, k<512; lw2 is [512][256]
    int n = i >> 9, k = i & 511;
    Wb2[i] = f2bf(lw2[(size_t)k * 256 + n]);
  }
  if (i < 128 * 128) {             // W2h/W2l[n][k]; W2 is [128][128]
    int n = i >> 7, k = i & 127;
    float w = W2[(size_t)k * 128 + n];
    unsigned short h = f2bf(w);
    W2h[i] = h;
    W2l[i] = f2bf(w - bf2f(h));
  }
}

// ---------------- F1: layer-1 GEMM (blocks [0,gblocks)) || rank (rest) ------
// tgemm1: hb[M,128] = bf16(x[M,64] @ W1[64,128]); rank: degree count + rank.
// The rank blocks are atomic-latency-bound (VALU ~0%); co-residency with the
// compute-bound GEMM blocks hides the GEMM entirely under the atomic pass.
// NOTE: keep this epilogue minimal — fusing alphas here (round 4) pushed the
// critical dispatch 80->93 us; alphas1 rides the place launch instead.
__launch_bounds__(256)
__global__ void gr_fused_kernel(const float* __restrict__ x, const float* __restrict__ W1,
                                unsigned short* __restrict__ hb, int M, int gblocks,
                                const int* __restrict__ dst, int* __restrict__ cnt,
                                unsigned short* __restrict__ rank, int E) {
  __shared__ float As[16][132];
  __shared__ float Bs[16][136];
  int bid = blockIdx.x;
  int t = threadIdx.x;

  if (bid >= gblocks) {
    int e = (bid - gblocks) * 256 + t;
    if (e < E) {
      int r = atomicAdd(&cnt[dst[e]], 1);
      rank[e] = (unsigned short)r;
    }
    return;
  }

  // ---- tgemm specialized: K=64, Nt=128, A f32, C bf16, no bias, no relu ----
  int tx = t & 15, ty = t >> 4;
  int m0 = bid * 128;

  float acc[8][8];
#pragma unroll
  for (int i = 0; i < 8; i++)
#pragma unroll
    for (int j = 0; j < 8; j++) acc[i][j] = 0.0f;

  int arow = t >> 1;
  int akc  = (t & 1) * 8;
  int bkk  = t >> 4;
  int bnn  = (t & 15) * 8;
  int gm = m0 + arow;

  for (int k0 = 0; k0 < 64; k0 += 16) {
    float av[8];
    if (gm < M) {
      const float* Af = x + (size_t)gm * 64 + k0 + akc;
      float4 r0 = *(const float4*)Af;
      float4 r1 = *(const float4*)(Af + 4);
      av[0] = r0.x; av[1] = r0.y; av[2] = r0.z; av[3] = r0.w;
      av[4] = r1.x; av[5] = r1.y; av[6] = r1.z; av[7] = r1.w;
    } else {
#pragma unroll
      for (int j = 0; j < 8; j++) av[j] = 0.0f;
    }
#pragma unroll
    for (int j = 0; j < 8; j++) As[akc + j][arow] = av[j];

    const float* bp = W1 + (size_t)(k0 + bkk) * 128 + bnn;
    float4 b0 = *(const float4*)bp;
    float4 b1 = *(const float4*)(bp + 4);
    *(float4*)&Bs[bkk][bnn]     = b0;
    *(float4*)&Bs[bkk][bnn + 4] = b1;

    __syncthreads();

#pragma unroll 4
    for (int kk = 0; kk < 16; kk++) {
      float a[8], b[8];
      *(float4*)&a[0] = *(const float4*)&As[kk][ty * 8];
      *(float4*)&a[4] = *(const float4*)&As[kk][ty * 8 + 4];
      *(float4*)&b[0] = *(const float4*)&Bs[kk][tx * 8];
      *(float4*)&b[4] = *(const float4*)&Bs[kk][tx * 8 + 4];
#pragma unroll
      for (int i = 0; i < 8; i++)
#pragma unroll
        for (int j = 0; j < 8; j++)
          acc[i][j] = fmaf(a[i], b[j], acc[i][j]);
    }
    __syncthreads();
  }

#pragma unroll
  for (int i = 0; i < 8; i++) {
    int m = m0 + ty * 8 + i;
    if (m >= M) continue;
    unsigned short* Cp = hb + (size_t)m * 128 + tx * 8;
    uint4 pk;
    pk.x = (unsigned int)f2bf(acc[i][0]) | ((unsigned int)f2bf(acc[i][1]) << 16);
    pk.y = (unsigned int)f2bf(acc[i][2]) | ((unsigned int)f2bf(acc[i][3]) << 16);
    pk.z = (unsigned int)f2bf(acc[i][4]) | ((unsigned int)f2bf(acc[i][5]) << 16);
    pk.w = (unsigned int)f2bf(acc[i][6]) | ((unsigned int)f2bf(acc[i][7]) << 16);
    *(uint4*)Cp = pk;
  }
}

// ---------------- CSR scan chain (2 launches; scan3 folded into consumers) ---
// NOTE: single-launch chained scan (round 7) was 243 us — 196 serial
// cross-XCD atomic hops at ~1.2 us each. Never serialize blocks on MI355X.
// offs holds within-block-256 exclusive prefix; true offset = offs[i]+bsum[i>>8].
__global__ void scan1_kernel(const int* __restrict__ cnt, int* __restrict__ offs,
                             int* __restrict__ bsum, int M) {
  __shared__ int sh[256];
  int t = threadIdx.x;
  int i = blockIdx.x * 256 + t;
  int v = (i < M) ? cnt[i] : 0;
  sh[t] = v;
  __syncthreads();
  for (int off = 1; off < 256; off <<= 1) {
    int u = (t >= off) ? sh[t - off] : 0;
    __syncthreads();
    sh[t] += u;
    __syncthreads();
  }
  if (i <= M) offs[i] = sh[t] - v;
  if (t == 255) bsum[blockIdx.x] = sh[255];
}

__global__ void scan2_kernel(int* __restrict__ bsum, int NB) {
  __shared__ int sh[256];
  int t = threadIdx.x;
  int v = (t < NB) ? bsum[t] : 0;
  sh[t] = v;
  __syncthreads();
  for (int off = 1; off < 256; off <<= 1) {
    int u = (t >= off) ? sh[t - off] : 0;
    __syncthreads();
    sh[t] += u;
    __syncthreads();
  }
  if (t < NB) bsum[t] = sh[t] - v;
}

// ---------------- F2: alphas layer1 (blocks [0,ablocks)) || place (rest) ----
// place: regular store (NOT nontemporal — nt hint on a random 4B scatter
// defeats L2 write merging; csr is 6.4MB and fully cache-resident).
__global__ void pa_fused_kernel(const unsigned short* __restrict__ hb,
                                const float* __restrict__ a_src,
                                const float* __restrict__ a_dst,
                                float2* __restrict__ aSp, float2* __restrict__ aDp,
                                int M, int ablocks,
                                const int* __restrict__ src, const int* __restrict__ dstp,
                                const unsigned short* __restrict__ rank,
                                const int* __restrict__ offs, const int* __restrict__ bsum,
                                int* __restrict__ csr, int E) {
  int bid = blockIdx.x;
  int t = threadIdx.x;

  if (bid >= ablocks) {
    int e = (bid - ablocks) * 256 + t;
    if (e < E) {
      int d = dstp[e];
      int p = offs[d] + bsum[d >> 8] + (int)rank[e];
      csr[p] = src[e];
    }
    return;
  }

  int gw = (bid * 256 + t) >> 6;
  int lane = t & 63;
  if (gw >= M) return;
  float h0 = bf2f(hb[(size_t)gw * 128 + lane]);
  float h1 = bf2f(hb[(size_t)gw * 128 + 64 + lane]);
  float as0 = h0 * a_src[lane];
  float as1 = h1 * a_src[64 + lane];
  float ad0 = h0 * a_dst[lane];
  float ad1 = h1 * a_dst[64 + lane];
  for (int o = 32; o; o >>= 1) {
    as0 += __shfl_xor(as0, o);
    as1 += __shfl_xor(as1, o);
    ad0 += __shfl_xor(ad0, o);
    ad1 += __shfl_xor(ad1, o);
  }
  if (lane == 0) {
    aSp[gw] = make_float2(as0, as1);
    aDp[gw] = make_float2(ad0, ad1);
  }
}

// ---------------- MFMA bf16 GEMM, m97 structure (MLP path) -------------------
// 128x128 tile, BK=32, 4 waves (2x2), 4x4 fragments of 16x16x32 per wave.
// B prepacked bf16 [Nt][K] staged via global_load_lds width=16; A direct-to-LDS
// when bf16, reg-staged f32->bf16 when f32. XCD-chunked work map (blockIdx.x =
// XCD = linear id % 8) so each A panel is fetched into exactly one XCD L2.
// Epilogue: two-pass LDS re-layout then cooperative uint4 stores (full 128B
// HBM lines; direct 2B stores caused 2.4x write amplification).
__launch_bounds__(256)
__global__ void m128_kernel(const void* __restrict__ A,
                            const unsigned short* __restrict__ Bw,
                            const float* __restrict__ bias, void* __restrict__ C,
                            int M, int K, int Nt, int aBF, int cBF, int relu,
                            int mtiles, int lgNB) {
  __shared__ unsigned short sh[8704];            // staging 16 KB / epilogue 128x68
  unsigned short* As = sh;                       // 128*32
  unsigned short* Bs = sh + 4096;                // 128*32
  int tid = threadIdx.x;
  int wid = tid >> 6, lane = tid & 63;
  int lm = lane & 15, quad = lane >> 4;
  int wr = wid >> 1, wc = wid & 1;

  // ---- XCD-chunked (m,n) tile assignment ----
  int xcd = blockIdx.x;                          // == linear dispatch id % 8
  int slot = blockIdx.y;
  int qm = mtiles >> 3, rm = mtiles & 7;
  int cntm = qm + (xcd < rm);
  int mstart = xcd * qm + (xcd < rm ? xcd : rm);
  if (slot >= (cntm << lgNB)) return;
  int NBm1 = (1 << lgNB) - 1;
  int m0 = (mstart + (slot >> lgNB)) * 128;
  int n0 = (slot & NBm1) * 128;

  f32x4 acc[4][4];
#pragma unroll
  for (int mi = 0; mi < 4; mi++)
#pragma unroll
    for (int ni = 0; ni < 4; ni++)
#pragma unroll
      for (int i = 0; i < 4; i++) acc[mi][ni][i] = 0.0f;

  // staging ids
  int c0 = (wid << 6) + lane;       // chunk ids for direct-to-LDS 16B loads
  int c1 = c0 + 256;
  int srow = tid >> 1;              // reg-stage (aBF=0): row 0..127
  int skc  = (tid & 1) << 4;        // k sub-offset 0/16 (16 floats each)

  for (int k0 = 0; k0 < K; k0 += 32) {
    // ---- B tile: 128 n-rows x 32 k, linear LDS, 2x global_load_lds / thread
    {
      const unsigned short* g0 = Bw + (size_t)(n0 + (c0 >> 2)) * K + k0 + ((c0 & 3) << 3);
      __builtin_amdgcn_global_load_lds((const __attribute__((address_space(1))) void*)g0,
                                       (__attribute__((address_space(3))) void*)(Bs + (wid << 9)),
                                       16, 0, 0);
      const unsigned short* g1 = Bw + (size_t)(n0 + (c1 >> 2)) * K + k0 + ((c1 & 3) << 3);
      __builtin_amdgcn_global_load_lds((const __attribute__((address_space(1))) void*)g1,
                                       (__attribute__((address_space(3))) void*)(Bs + 2048 + (wid << 9)),
                                       16, 0, 0);
    }
    // ---- A tile
    if (aBF) {
      int r0 = m0 + (c0 >> 2); if (r0 > M - 1) r0 = M - 1;   // clamp tail (rows >= M never written)
      const unsigned short* g0 = (const unsigned short*)A + (size_t)r0 * K + k0 + ((c0 & 3) << 3);
      __builtin_amdgcn_global_load_lds((const __attribute__((address_space(1))) void*)g0,
                                       (__attribute__((address_space(3))) void*)(As + (wid << 9)),
                                       16, 0, 0);
      int r1 = m0 + (c1 >> 2); if (r1 > M - 1) r1 = M - 1;
      const unsigned short* g1 = (const unsigned short*)A + (size_t)r1 * K + k0 + ((c1 & 3) << 3);
      __builtin_amdgcn_global_load_lds((const __attribute__((address_space(1))) void*)g1,
                                       (__attribute__((address_space(3))) void*)(As + 2048 + (wid << 9)),
                                       16, 0, 0);
    } else {
      int gm = m0 + srow;
      uint4 p0, p1;
      if (gm < M) {
        const float* Af = (const float*)A + (size_t)gm * K + k0 + skc;
        float4 r0 = *(const float4*)Af;
        float4 r1 = *(const float4*)(Af + 4);
        float4 r2 = *(const float4*)(Af + 8);
        float4 r3 = *(const float4*)(Af + 12);
        p0.x = (unsigned int)f2bf(r0.x) | ((unsigned int)f2bf(r0.y) << 16);
        p0.y = (unsigned int)f2bf(r0.z) | ((unsigned int)f2bf(r0.w) << 16);
        p0.z = (unsigned int)f2bf(r1.x) | ((unsigned int)f2bf(r1.y) << 16);
        p0.w = (unsigned int)f2bf(r1.z) | ((unsigned int)f2bf(r1.w) << 16);
        p1.x = (unsigned int)f2bf(r2.x) | ((unsigned int)f2bf(r2.y) << 16);
        p1.y = (unsigned int)f2bf(r2.z) | ((unsigned int)f2bf(r2.w) << 16);
        p1.z = (unsigned int)f2bf(r3.x) | ((unsigned int)f2bf(r3.y) << 16);
        p1.w = (unsigned int)f2bf(r3.z) | ((unsigned int)f2bf(r3.w) << 16);
      } else {
        p0.x = p0.y = p0.z = p0.w = 0u;
        p1.x = p1.y = p1.z = p1.w = 0u;
      }
      *(uint4*)&As[srow * 32 + skc] = p0;
      *(uint4*)&As[srow * 32 + skc + 8] = p1;
    }
    __syncthreads();

    bf16f afr[4], bfr[4];
#pragma unroll
    for (int mi = 0; mi < 4; mi++)
      afr[mi] = *(const bf16f*)&As[(wr * 64 + mi * 16 + lm) * 32 + quad * 8];
#pragma unroll
    for (int ni = 0; ni < 4; ni++)
      bfr[ni] = *(const bf16f*)&Bs[(wc * 64 + ni * 16 + lm) * 32 + quad * 8];
#pragma unroll
    for (int mi = 0; mi < 4; mi++)
#pragma unroll
      for (int ni = 0; ni < 4; ni++)
        acc[mi][ni] = __builtin_amdgcn_mfma_f32_16x16x32_bf16(afr[mi], bfr[ni], acc[mi][ni], 0, 0, 0);
    __syncthreads();
  }

  if (cBF) {
    // ---- two-pass LDS-staged coalesced bf16 epilogue ----
#pragma unroll
    for (int p = 0; p < 2; p++) {
      __syncthreads();
      if (wc == p) {
#pragma unroll
        for (int ni = 0; ni < 4; ni++) {
          int colb = ni * 16 + lm;                      // 0..63 within pass
          float bv = (bias != 0) ? bias[n0 + p * 64 + colb] : 0.0f;
#pragma unroll
          for (int mi = 0; mi < 4; mi++) {
#pragma unroll
            for (int i = 0; i < 4; i++) {
              int rowb = wr * 64 + mi * 16 + quad * 4 + i;
              float v = acc[mi][ni][i] + bv;
              if (relu) v = fmaxf(v, 0.0f);
              sh[rowb * 68 + colb] = f2bf(v);
            }
          }
        }
      }
      __syncthreads();
#pragma unroll
      for (int sweep = 0; sweep < 4; sweep++) {
        int rowb = (tid >> 3) + 32 * sweep;
        int seg = tid & 7;
        int grow = m0 + rowb;
        if (grow < M) {
          uint4 val = *(const uint4*)&sh[rowb * 68 + seg * 8];
          *(uint4*)((unsigned short*)C + (size_t)grow * Nt + n0 + p * 64 + seg * 8) = val;
        }
      }
    }
  } else {
    // f32 fallback (unused in current launches)
#pragma unroll
    for (int ni = 0; ni < 4; ni++) {
      int col = n0 + wc * 64 + ni * 16 + lm;
      float bv = (bias != 0) ? bias[col] : 0.0f;
#pragma unroll
      for (int mi = 0; mi < 4; mi++) {
#pragma unroll
        for (int i = 0; i < 4; i++) {
          int row = m0 + wr * 64 + mi * 16 + quad * 4 + i;
          if (row < M) {
            float v = acc[mi][ni][i] + bv;
            if (relu) v = fmaxf(v, 0.0f);
            ((float*)C)[(size_t)row * Nt + col] = v;
          }
        }
      }
    }
  }
}

// ---------------- layer-2 GEMM: 3-term split-precision bf16 MFMA ------------
// hb[M,128] = bf16(x2[M,128] @ W2[128,128]), f32-class accuracy.
// A comes prepacked hi/lo bf16 from aggregate1 (x2h/x2l); all tiles stage via
// global_load_lds. BM=64, 4 waves 2x2, fused alphas2.
__launch_bounds__(256)
__global__ void tg2m_kernel(const unsigned short* __restrict__ Ahp,
                            const unsigned short* __restrict__ Alp,
                            const unsigned short* __restrict__ Bh,
                            const unsigned short* __restrict__ Bl,
                            const float* __restrict__ a_src, const float* __restrict__ a_dst,
                            unsigned short* __restrict__ hb,
                            float2* __restrict__ aSp, float2* __restrict__ aDp,
                            int M) {
  __shared__ unsigned short sh[12288];          // 24 KB
  unsigned short* Ah = sh;                      // 64*32
  unsigned short* Al = sh + 2048;
  unsigned short* BH = sh + 4096;               // 128*32
  unsigned short* BL = sh + 8192;
  const int K = 128;
  int tid = threadIdx.x;
  int wid = tid >> 6, lane = tid & 63;
  int lm = lane & 15, quad = lane >> 4;
  int wr = wid >> 1, wc = wid & 1;
  int m0 = blockIdx.x * 64;

  f32x4 acc[2][4];
#pragma unroll
  for (int mi = 0; mi < 2; mi++)
#pragma unroll
    for (int ni = 0; ni < 4; ni++)
#pragma unroll
      for (int i = 0; i < 4; i++) acc[mi][ni][i] = 0.0f;

  int c0 = (wid << 6) + lane, c1 = c0 + 256;

  for (int k0 = 0; k0 < K; k0 += 32) {
    // B hi/lo tiles: 128 n-rows x 32 k each, direct-to-LDS
    {
      const unsigned short* g0 = Bh + (size_t)(c0 >> 2) * K + k0 + ((c0 & 3) << 3);
      __builtin_amdgcn_global_load_lds((const __attribute__((address_space(1))) void*)g0,
                                       (__attribute__((address_space(3))) void*)(BH + (wid << 9)),
                                       16, 0, 0);
      const unsigned short* g1 = Bh + (size_t)(c1 >> 2) * K + k0 + ((c1 & 3) << 3);
      __builtin_amdgcn_global_load_lds((const __attribute__((address_space(1))) void*)g1,
                                       (__attribute__((address_space(3))) void*)(BH + 2048 + (wid << 9)),
                                       16, 0, 0);
      const unsigned short* g2 = Bl + (size_t)(c0 >> 2) * K + k0 + ((c0 & 3) << 3);
      __builtin_amdgcn_global_load_lds((const __attribute__((address_space(1))) void*)g2,
                                       (__attribute__((address_space(3))) void*)(BL + (wid << 9)),
                                       16, 0, 0);
      const unsigned short* g3 = Bl + (size_t)(c1 >> 2) * K + k0 + ((c1 & 3) << 3);
      __builtin_amdgcn_global_load_lds((const __attribute__((address_space(1))) void*)g3,
                                       (__attribute__((address_space(3))) void*)(BL + 2048 + (wid << 9)),
                                       16, 0, 0);
    }
    // A hi/lo tiles: 64 rows x 32 k, direct-to-LDS (256 chunks = whole tile)
    {
      int r0 = m0 + (c0 >> 2); if (r0 > M - 1) r0 = M - 1;   // tail clamp
      const unsigned short* g0 = Ahp + (size_t)r0 * K + k0 + ((c0 & 3) << 3);
      __builtin_amdgcn_global_load_lds((const __attribute__((address_space(1))) void*)g0,
                                       (__attribute__((address_space(3))) void*)(Ah + (wid << 9)),
                                       16, 0, 0);
      const unsigned short* g1 = Alp + (size_t)r0 * K + k0 + ((c0 & 3) << 3);
      __builtin_amdgcn_global_load_lds((const __attribute__((address_space(1))) void*)g1,
                                       (__attribute__((address_space(3))) void*)(Al + (wid << 9)),
                                       16, 0, 0);
    }
    __syncthreads();

    bf16f ahf[2], alf[2];
#pragma unroll
    for (int mi = 0; mi < 2; mi++) {
      ahf[mi] = *(const bf16f*)&Ah[(wr * 32 + mi * 16 + lm) * 32 + quad * 8];
      alf[mi] = *(const bf16f*)&Al[(wr * 32 + mi * 16 + lm) * 32 + quad * 8];
    }
#pragma unroll
    for (int ni = 0; ni < 4; ni++) {
      bf16f vbh = *(const bf16f*)&BH[(wc * 64 + ni * 16 + lm) * 32 + quad * 8];
      bf16f vbl = *(const bf16f*)&BL[(wc * 64 + ni * 16 + lm) * 32 + quad * 8];
#pragma unroll
      for (int mi = 0; mi < 2; mi++) {
        acc[mi][ni] = __builtin_amdgcn_mfma_f32_16x16x32_bf16(ahf[mi], vbh, acc[mi][ni], 0, 0, 0);
        acc[mi][ni] = __builtin_amdgcn_mfma_f32_16x16x32_bf16(alf[mi], vbh, acc[mi][ni], 0, 0, 0);
        acc[mi][ni] = __builtin_amdgcn_mfma_f32_16x16x32_bf16(ahf[mi], vbl, acc[mi][ni], 0, 0, 0);
      }
    }
    __syncthreads();
  }

  // ---- epilogue: two col-passes; coalesced hb stores + fused alphas --------
  float ps[2], pd[2];
#pragma unroll
  for (int p = 0; p < 2; p++) {
    __syncthreads();
    if (wc == p) {
#pragma unroll
      for (int ni = 0; ni < 4; ni++) {
        int colb = ni * 16 + lm;
#pragma unroll
        for (int mi = 0; mi < 2; mi++)
#pragma unroll
          for (int i = 0; i < 4; i++) {
            int rowb = wr * 32 + mi * 16 + quad * 4 + i;
            sh[rowb * 72 + colb] = f2bf(acc[mi][ni][i]);
          }
      }
    }
    __syncthreads();
    // coalesced store: 64 rows x 64 cols (8 x uint4 per row)
#pragma unroll
    for (int sweep = 0; sweep < 2; sweep++) {
      int rowb = (tid >> 3) + 32 * sweep;
      int seg = tid & 7;
      int grow = m0 + rowb;
      if (grow < M) {
        uint4 val = *(const uint4*)&sh[rowb * 72 + seg * 8];
        *(uint4*)(hb + (size_t)grow * 128 + p * 64 + seg * 8) = val;
      }
    }
    // alphas partials for head p: 4 threads/row x 16 cols
    {
      int row = tid >> 2, sg = tid & 3;
      const float* As_ = a_src + p * 64 + sg * 16;
      const float* Ad_ = a_dst + p * 64 + sg * 16;
      float s = 0.0f, d = 0.0f;
#pragma unroll
      for (int c8 = 0; c8 < 2; c8++) {
        uint4 rv = *(const uint4*)&sh[row * 72 + sg * 16 + c8 * 8];
        const float* Ap_ = As_ + c8 * 8;
        const float* Dp_ = Ad_ + c8 * 8;
        float hv[8];
        hv[0] = bflo(rv.x); hv[1] = bfhi(rv.x);
        hv[2] = bflo(rv.y); hv[3] = bfhi(rv.y);
        hv[4] = bflo(rv.z); hv[5] = bfhi(rv.z);
        hv[6] = bflo(rv.w); hv[7] = bfhi(rv.w);
#pragma unroll
        for (int j = 0; j < 8; j++) {
          s = fmaf(hv[j], Ap_[j], s);
          d = fmaf(hv[j], Dp_[j], d);
        }
      }
      s += __shfl_xor(s, 1); s += __shfl_xor(s, 2);
      d += __shfl_xor(d, 1); d += __shfl_xor(d, 2);
      ps[p] = s; pd[p] = d;
    }
  }
  {
    int row = tid >> 2, sg = tid & 3;
    int m = m0 + row;
    if (sg == 0 && m < M) {
      aSp[m] = make_float2(ps[0], ps[1]);
      aDp[m] = make_float2(pd[0], pd[1]);
    }
  }
}

// ---------------- MFMA logits GEMM: C[M,16] = A[M,K]@W[K,16] + bias ----------
__launch_bounds__(256)
__global__ void lgemm_kernel(const unsigned short* __restrict__ A,
                             const float* __restrict__ W,
                             const float* __restrict__ bias, float* __restrict__ C,
                             int M, int K) {
  __shared__ unsigned short Bt[16 * 264];
  int tid = threadIdx.x;
  int wave = tid >> 6, lane = tid & 63;
  int lm = lane & 15, quad = lane >> 4;
  int m0 = blockIdx.x * 64;

  // stage W (K x 16 f32) -> Bt[n][k] bf16
  for (int f0 = tid * 4; f0 < K * 16; f0 += 1024) {
    float4 w4 = *(const float4*)(W + f0);
    int k = f0 >> 4, n = f0 & 15;
    Bt[(n + 0) * 264 + k] = f2bf(w4.x);
    Bt[(n + 1) * 264 + k] = f2bf(w4.y);
    Bt[(n + 2) * 264 + k] = f2bf(w4.z);
    Bt[(n + 3) * 264 + k] = f2bf(w4.w);
  }
  __syncthreads();

  f32x4 acc;
#pragma unroll
  for (int i = 0; i < 4; i++) acc[i] = 0.0f;

  int m = m0 + wave * 16 + lm;                 // A-operand row for this lane
  const unsigned short* Ap = A + (size_t)m * K;

  for (int k0 = 0; k0 < K; k0 += 32) {
    bf16f af;
#pragma unroll
    for (int j = 0; j < 8; j++) af[j] = (__bf16)0.0f;
    if (m < M) af = *(const bf16f*)(Ap + k0 + quad * 8);
    bf16f bfv = *(const bf16f*)&Bt[lm * 264 + k0 + quad * 8];
    acc = __builtin_amdgcn_mfma_f32_16x16x32_bf16(af, bfv, acc, 0, 0, 0);
  }

  float bv = bias[lm];
#pragma unroll
  for (int i = 0; i < 4; i++) {
    int row = m0 + wave * 16 + quad * 4 + i;
    if (row < M) C[(size_t)row * 16 + lm] = acc[i] + bv;
  }
}

// ---------------- per-node softmax aggregation (bf16 gather) -----------------
// Epilogue writes any of: f32 out, bf16-hi out, bf16-lo out (nullable).
// offs is partial (scan3 folded): true offset = offs[i] + bsum[i>>8].
__global__ void aggregate_kernel(const unsigned short* __restrict__ hb,
                                 const float2* __restrict__ aSp,
                                 const float2* __restrict__ aDp,
                                 const int* __restrict__ csr_src, const int* __restrict__ offs,
                                 const int* __restrict__ bsum,
                                 const float* __restrict__ bias,
                                 float* __restrict__ outf,
                                 unsigned short* __restrict__ outh,
                                 unsigned short* __restrict__ outl, int M) {
  int n = (blockIdx.x * blockDim.x + threadIdx.x) >> 6;
  int lane = threadIdx.x & 63;
  if (n >= M) return;
  int g = lane >> 4;
  int q = lane & 15;
  int h0sel = (q < 8);

  float2 adn = aDp[n];
  float2 asn = aSp[n];
  float e0 = asn.x + adn.x; e0 = (e0 > 0.0f) ? e0 : 0.2f * e0;   // leaky_relu 0.2
  float e1 = asn.y + adn.y; e1 = (e1 > 0.0f) ? e1 : 0.2f * e1;
  float ws0 = expf(e0), ws1 = expf(e1);
  float wself = h0sel ? ws0 : ws1;

  float acc[8];
  if (g == 0) {
    uint4 rv = *(const uint4*)(hb + (size_t)n * 128 + q * 8);
    acc[0] = wself * bflo(rv.x); acc[1] = wself * bfhi(rv.x);
    acc[2] = wself * bflo(rv.y); acc[3] = wself * bfhi(rv.y);
    acc[4] = wself * bflo(rv.z); acc[5] = wself * bfhi(rv.z);
    acc[6] = wself * bflo(rv.w); acc[7] = wself * bfhi(rv.w);
  } else {
#pragma unroll
    for (int i = 0; i < 8; i++) acc[i] = 0.0f;
  }

  float lp0 = 0.0f, lp1 = 0.0f;
  int rs = offs[n] + bsum[n >> 8];
  int re = offs[n + 1] + bsum[(n + 1) >> 8];
  for (int base = rs; base < re; base += 64) {
    int cnt = re - base; if (cnt > 64) cnt = 64;
    int s = 0; float w0 = 0.0f, w1 = 0.0f;
    if (lane < cnt) {
      s = csr_src[base + lane];
      float2 a = aSp[s];
      float f0 = a.x + adn.x; f0 = (f0 > 0.0f) ? f0 : 0.2f * f0;
      float f1 = a.y + adn.y; f1 = (f1 > 0.0f) ? f1 : 0.2f * f1;
      w0 = expf(f0); w1 = expf(f1);
      lp0 += w0; lp1 += w1;
    }
    int jmax = (cnt + 3) >> 2;
#pragma unroll 8
    for (int j = 0; j < jmax; j++) {
      int el = 4 * j + g;
      int sj  = __shfl(s, el);
      float w0j = __shfl(w0, el);
      float w1j = __shfl(w1, el);
      float wj = h0sel ? w0j : w1j;
      uint4 rv = *(const uint4*)(hb + (size_t)sj * 128 + q * 8);
      acc[0] = fmaf(wj, bflo(rv.x), acc[0]);
      acc[1] = fmaf(wj, bfhi(rv.x), acc[1]);
      acc[2] = fmaf(wj, bflo(rv.y), acc[2]);
      acc[3] = fmaf(wj, bfhi(rv.y), acc[3]);
      acc[4] = fmaf(wj, bflo(rv.z), acc[4]);
      acc[5] = fmaf(wj, bfhi(rv.z), acc[5]);
      acc[6] = fmaf(wj, bflo(rv.w), acc[6]);
      acc[7] = fmaf(wj, bfhi(rv.w), acc[7]);
    }
  }
#pragma unroll
  for (int i = 0; i < 8; i++) {
    acc[i] += __shfl_xor(acc[i], 16);
    acc[i] += __shfl_xor(acc[i], 32);
  }
  for (int o = 32; o; o >>= 1) {
    lp0 += __shfl_xor(lp0, o);
    lp1 += __shfl_xor(lp1, o);
  }
  if (g == 0) {
    float linv = 1.0f / ((h0sel ? lp0 + ws0 : lp1 + ws1) + 1e-16f);
    const float* bp = bias + q * 8;
    float v[8];
#pragma unroll
    for (int i = 0; i < 8; i++) v[i] = fmaxf(acc[i] * linv + bp[i], 0.0f);
    if (outf) {
      float4 o0, o1;
      o0.x = v[0]; o0.y = v[1]; o0.z = v[2]; o0.w = v[3];
      o1.x = v[4]; o1.y = v[5]; o1.z = v[6]; o1.w = v[7];
      float* op = outf + (size_t)n * 128 + q * 8;
      *(float4*)op = o0;
      *(float4*)(op + 4) = o1;
    }
    if (outh) {
      unsigned short hh[8];
#pragma unroll
      for (int i = 0; i < 8; i++) hh[i] = f2bf(v[i]);
      uint4 ph;
      ph.x = (unsigned int)hh[0] | ((unsigned int)hh[1] << 16);
      ph.y = (unsigned int)hh[2] | ((unsigned int)hh[3] << 16);
      ph.z = (unsigned int)hh[4] | ((unsigned int)hh[5] << 16);
      ph.w = (unsigned int)hh[6] | ((unsigned int)hh[7] << 16);
      *(uint4*)(outh + (size_t)n * 128 + q * 8) = ph;
      if (outl) {
        unsigned short ll[8];
#pragma unroll
        for (int i = 0; i < 8; i++) ll[i] = f2bf(v[i] - bf2f(hh[i]));
        uint4 pl;
        pl.x = (unsigned int)ll[0] | ((unsigned int)ll[1] << 16);
        pl.y = (unsigned int)ll[2] | ((unsigned int)ll[3] << 16);
        pl.z = (unsigned int)ll[4] | ((unsigned int)ll[5] << 16);
        pl.w = (unsigned int)ll[6] | ((unsigned int)ll[7] << 16);
        *(uint4*)(outl + (size_t)n * 128 + q * 8) = pl;
      }
    }
  }
}

extern "C" void kernel_launch(void* const* d_in, const int* in_sizes, int n_in,
                              void* d_out, int out_size, void* d_ws, size_t ws_size,
                              hipStream_t stream) {
  const int N = in_sizes[0] / 64;   // 50000
  const int E = in_sizes[1] / 2;    // 1,600,000
  const float* x   = (const float*)d_in[0];
  const int*   ei  = (const int*)d_in[1];
  const float* W1  = (const float*)d_in[2];
  const float* as1 = (const float*)d_in[3];
  const float* ad1 = (const float*)d_in[4];
  const float* b1  = (const float*)d_in[5];
  const float* W2  = (const float*)d_in[6];
  const float* as2 = (const float*)d_in[7];
  const float* ad2 = (const float*)d_in[8];
  const float* b2  = (const float*)d_in[9];
  const float* lw1 = (const float*)d_in[10];
  const float* lb1 = (const float*)d_in[11];
  const float* lw2 = (const float*)d_in[12];
  const float* lb2 = (const float*)d_in[13];
  const float* lw3 = (const float*)d_in[14];
  const float* lb3 = (const float*)d_in[15];

  float* emb    = (float*)d_out;                    // N*128 f32
  float* logits = (float*)d_out + (size_t)N * 128;  // N*16 f32

  // ---- workspace layout ----
  // persistent (live across phases): prepacked weights
  char* base = (char*)d_ws;
  size_t o = 0;
  unsigned short* Wb1 = (unsigned short*)(base + o); o += ((size_t)512 * 128 * 2 + 255) & ~(size_t)255; // [512][128]
  unsigned short* Wb2 = (unsigned short*)(base + o); o += ((size_t)256 * 512 * 2 + 255) & ~(size_t)255; // [256][512]
  unsigned short* W2h = (unsigned short*)(base + o); o += ((size_t)128 * 128 * 2 + 255) & ~(size_t)255; // [128][128]
  unsigned short* W2l = (unsigned short*)(base + o); o += ((size_t)128 * 128 * 2 + 255) & ~(size_t)255;
  char* tb = base + o;   // transient region (phase1 / phase2 overlay)

  size_t a128 = ((size_t)N * 128 * 2 + 255) & ~(size_t)255;   // 12.8 MB unit
  size_t t = 0;
  unsigned short* hb = (unsigned short*)(tb + t); t += a128;
  unsigned short* x2h = (unsigned short*)(tb + t); t += a128;
  unsigned short* x2l = (unsigned short*)(tb + t); t += a128;
  float2* aSp = (float2*)(tb + t); t += ((size_t)N * 8 + 255) & ~(size_t)255;
  float2* aDp = (float2*)(tb + t); t += ((size_t)N * 8 + 255) & ~(size_t)255;
  int* cnt  = (int*)(tb + t); t += ((size_t)N * 4 + 255) & ~(size_t)255;
  int* offs = (int*)(tb + t); t += ((size_t)(N + 1) * 4 + 255) & ~(size_t)255;
  int* bsum = (int*)(tb + t); t += ((size_t)256 * 4 + 255) & ~(size_t)255;
  unsigned short* rank = (unsigned short*)(tb + t); t += ((size_t)E * 2 + 255) & ~(size_t)255;
  int* csr  = (int*)(tb + t); t += ((size_t)E * 4 + 255) & ~(size_t)255;
  // phase 2 (MLP head; emb already in d_out) overlays:
  //   embb (bf16 emb copy, written by agg2)  -> x2h region [a128, 2*a128)
  //   z1b (N*512 bf16, m128#1 out)           -> [2*a128, ...)  (x2l.. dead)
  //   z2b (N*256 bf16, m128#2 out)           -> [0, ...)  (hb+embb dead by then)
  unsigned short* embb = x2h;
  unsigned short* z1b = (unsigned short*)(tb + 2 * a128);
  unsigned short* z2b = (unsigned short*)tb;

  const int* esrc = ei;
  const int* edst = ei + E;

  int eb = (E + 255) / 256;
  int sb = (N + 256) / 256;
  int nb4 = (N + 3) / 4;
  int mtb = (N + 127) / 128;
  int mtb64 = (N + 63) / 64;

  // prep: zero degree counters (canonical symbol) + fused weight prepack
  GNNModel_general_12077448036407_kernel<<<(N + 255) / 256, 256, 0, stream>>>(cnt, N);
  wpack3_kernel<<<512, 256, 0, stream>>>(lw1, Wb1, lw2, Wb2, W2, W2h, W2l);

  // F1: layer-1 GEMM (x @ W1 -> hb) overlapped with rank (atomic degree+rank)
  gr_fused_kernel<<<mtb + eb, 256, 0, stream>>>(x, W1, hb, N, mtb, edst, cnt, rank, E);

  // CSR scan chain (2 launches; scan3 folded into place/aggregate)
  scan1_kernel<<<sb, 256, 0, stream>>>(cnt, offs, bsum, N);
  scan2_kernel<<<1, 256, 0, stream>>>(bsum, sb);

  // F2: alphas layer-1 overlapped with CSR place
  pa_fused_kernel<<<nb4 + eb, 256, 0, stream>>>(hb, as1, ad1, aSp, aDp, N, nb4,
                                                esrc, edst, rank, offs, bsum, csr, E);

  // GAT layer 1 aggregation -> x2 (hi/lo bf16 prepack for tg2m)
  aggregate_kernel<<<nb4, 256, 0, stream>>>(hb, aSp, aDp, csr, offs, bsum, b1,
                                            (float*)0, x2h, x2l, N);

  // GAT layer 2 GEMM (3-term split-precision MFMA) + fused alphas2
  tg2m_kernel<<<mtb64, 256, 0, stream>>>(x2h, x2l, W2h, W2l, as2, ad2, hb, aSp, aDp, N);

  // GAT layer 2 aggregation -> emb (f32 output) + embb (bf16 copy for MLP)
  aggregate_kernel<<<nb4, 256, 0, stream>>>(hb, aSp, aDp, csr, offs, bsum, b2,
                                            emb, embb, (unsigned short*)0, N);

  // MLP head: 128 -> 512 -> 256 -> 16 (bf16 MFMA, 128x128 tiles, XCD-chunked)
  int qx = mtb >> 3, rx = mtb & 7;
  int spx = qx + (rx ? 1 : 0);
  m128_kernel<<<dim3(8, spx * 4), 256, 0, stream>>>(embb, Wb1, lb1, z1b,
                                                    N, 128, 512, 1, 1, 1, mtb, 2);
  m128_kernel<<<dim3(8, spx * 2), 256, 0, stream>>>(z1b, Wb2, lb2, z2b,
                                                    N, 512, 256, 1, 1, 1, mtb, 1);
  lgemm_kernel<<<mtb64, 256, 0, stream>>>(z2b, lw3, lb3, logits, N, 256);
}